// Round 1
// baseline (207.354 us; speedup 1.0000x reference)
//
#include <hip/hip_runtime.h>
#include <hip/hip_bf16.h>

typedef __bf16 bf16;
typedef __bf16 bf16x8 __attribute__((ext_vector_type(8)));
typedef __bf16 bf16x4 __attribute__((ext_vector_type(4)));
typedef float  f32x4  __attribute__((ext_vector_type(4)));
typedef int    i32x4  __attribute__((ext_vector_type(4)));

#define B_ 8
#define P_ 2048
#define Q_ 512
#define H_ 1024

__device__ __forceinline__ void gload_lds16(const void* g, void* l) {
  __builtin_amdgcn_global_load_lds(
      (const __attribute__((address_space(1))) void*)g,
      (__attribute__((address_space(3))) void*)l, 16, 0, 0);
}

// ---- f32 -> bf16 hi/lo split (exact: hi+lo error ~2^-17 rel) ----
__global__ __launch_bounds__(256) void k_split(const float* __restrict__ x,
                                               bf16* __restrict__ hi,
                                               bf16* __restrict__ lo, int n4) {
  int i = blockIdx.x * blockDim.x + threadIdx.x;
  int stride = gridDim.x * blockDim.x;
  for (; i < n4; i += stride) {
    f32x4 v = ((const f32x4*)x)[i];
    bf16x4 h, l;
#pragma unroll
    for (int j = 0; j < 4; ++j) {
      bf16 hj = (bf16)v[j];
      h[j] = hj;
      l[j] = (bf16)(v[j] - (float)hj);
    }
    ((bf16x4*)hi)[i] = h;
    ((bf16x4*)lo)[i] = l;
  }
}

__global__ __launch_bounds__(256) void k_cvt(const float* __restrict__ x,
                                             bf16* __restrict__ y, int n4) {
  int i = blockIdx.x * blockDim.x + threadIdx.x;
  int stride = gridDim.x * blockDim.x;
  for (; i < n4; i += stride) {
    f32x4 v = ((const f32x4*)x)[i];
    bf16x4 h;
#pragma unroll
    for (int j = 0; j < 4; ++j) h[j] = (bf16)v[j];
    ((bf16x4*)y)[i] = h;
  }
}

// ---- question [B,Q,H] f32 -> qT [B,H,Q] bf16 (64x64 LDS tile) ----
__global__ __launch_bounds__(256) void k_transpose(const float* __restrict__ q,
                                                   bf16* __restrict__ qT) {
  __shared__ float t[64][65];
  int b = blockIdx.z;
  int h0 = blockIdx.x * 64, q0 = blockIdx.y * 64;
  int tid = threadIdx.x;
  int c4 = (tid & 15) * 4;
  int r16 = tid >> 4;
  const float* src = q + ((long)b * Q_ + q0) * H_ + h0;
#pragma unroll
  for (int i = 0; i < 4; ++i) {
    int r = r16 + i * 16;
    f32x4 v = *(const f32x4*)(src + (long)r * H_ + c4);
    t[c4 + 0][r] = v[0];
    t[c4 + 1][r] = v[1];
    t[c4 + 2][r] = v[2];
    t[c4 + 3][r] = v[3];
  }
  __syncthreads();
  bf16* dst = qT + ((long)b * H_ + h0) * Q_ + q0;
#pragma unroll
  for (int i = 0; i < 4; ++i) {
    int hr = r16 + i * 16;
    bf16x4 o;
#pragma unroll
    for (int j = 0; j < 4; ++j) o[j] = (bf16)t[hr][c4 + j];
    *(bf16x4*)(dst + (long)hr * Q_ + c4) = o;
  }
}

// ---- masked softmax: alpha_q = m*e^{t-c} / (Sum(m*e) + 1e-13*Z), one wave/row ----
__global__ __launch_bounds__(256) void k_softmax(const float* __restrict__ S,
                                                 const int* __restrict__ qmask,
                                                 bf16* __restrict__ alpha) {
  int row = blockIdx.x * 4 + (threadIdx.x >> 6);
  int lane = threadIdx.x & 63;
  int b = row >> 11;  // P_=2048 rows per batch
  const float* s = S + (long)row * Q_;
  const int* mp = qmask + b * Q_;
  f32x4 v0 = ((const f32x4*)s)[lane * 2];
  f32x4 v1 = ((const f32x4*)s)[lane * 2 + 1];
  i32x4 m0 = ((const i32x4*)mp)[lane * 2];
  i32x4 m1 = ((const i32x4*)mp)[lane * 2 + 1];
  float t[8], mf[8];
#pragma unroll
  for (int j = 0; j < 4; ++j) {
    mf[j] = (float)m0[j];     t[j] = v0[j] * mf[j];
    mf[4 + j] = (float)m1[j]; t[4 + j] = v1[j] * mf[4 + j];
  }
  float mx = t[0];
#pragma unroll
  for (int j = 1; j < 8; ++j) mx = fmaxf(mx, t[j]);
  for (int o = 32; o; o >>= 1) mx = fmaxf(mx, __shfl_xor(mx, o, 64));
  float e[8], Z = 0.f, Sm = 0.f;
#pragma unroll
  for (int j = 0; j < 8; ++j) {
    e[j] = expf(t[j] - mx);
    Z += e[j];
    Sm += e[j] * mf[j];
  }
  for (int o = 32; o; o >>= 1) {
    Z += __shfl_xor(Z, o, 64);
    Sm += __shfl_xor(Sm, o, 64);
  }
  float inv = 1.0f / (Sm + 1e-13f * Z);
  bf16x8 out;
#pragma unroll
  for (int j = 0; j < 8; ++j) out[j] = (bf16)(e[j] * mf[j] * inv);
  *(bf16x8*)(alpha + (long)row * Q_ + lane * 8) = out;
}

// ---- m97-style 128x128 bf16 GEMM, A[M,K] * B[N,K]^T, BK=32, 4 waves ----
// SPLIT: 3-MFMA hi/lo split accumulation (f32-class precision for scores)
// EPI: 0 = f32 store, 1 = bf16 store, 2 = f32 bias+relu store
template <bool SPLIT, int EPI>
__global__ __launch_bounds__(256) void k_gemm_bt(
    const bf16* __restrict__ A, const bf16* __restrict__ Al,
    const bf16* __restrict__ Bm, const bf16* __restrict__ Bl,
    void* __restrict__ Cv, const float* __restrict__ bias,
    int M, int N, int K, int sA, int sB, int sC) {
  __shared__ __align__(16) bf16 smem[(SPLIT ? 4 : 2) * 4096];
  bf16* shA = smem;
  bf16* shB = smem + 4096;
  bf16* shAl = SPLIT ? smem + 8192 : nullptr;
  bf16* shBl = SPLIT ? smem + 12288 : nullptr;

  int tid = threadIdx.x, wv = tid >> 6, lane = tid & 63;
  int z = blockIdx.z;
  A += (long)z * sA;
  Bm += (long)z * sB;
  if constexpr (SPLIT) {
    Al += (long)z * sA;
    Bl += (long)z * sB;
  }
  int row0 = blockIdx.y * 128, col0 = blockIdx.x * 128;

  auto stage = [&](int k0) {
    int gr = tid >> 2;
    int gc = (tid & 3) * 8;
#pragma unroll
    for (int i = 0; i < 2; ++i) {
      long aoff = (long)(row0 + i * 64 + gr) * K + k0 + gc;
      long boff = (long)(col0 + i * 64 + gr) * K + k0 + gc;
      int loff = i * 2048 + wv * 512;  // wave-uniform LDS base (elements)
      gload_lds16(A + aoff, shA + loff);
      gload_lds16(Bm + boff, shB + loff);
      if constexpr (SPLIT) {
        gload_lds16(Al + aoff, shAl + loff);
        gload_lds16(Bl + boff, shBl + loff);
      }
    }
  };

  f32x4 acc[4][4] = {};
  stage(0);
  int nk = K / 32;
  int wr = (wv >> 1) * 64, wc = (wv & 1) * 64;
  int fr = lane & 15, kq = (lane >> 4) * 8;
  for (int ks = 0; ks < nk; ++ks) {
    __syncthreads();
    bf16x8 af[4], bfm[4], afl[4], bfl[4];
#pragma unroll
    for (int m = 0; m < 4; ++m) {
      af[m] = *(const bf16x8*)&shA[(wr + m * 16 + fr) * 32 + kq];
      if constexpr (SPLIT)
        afl[m] = *(const bf16x8*)&shAl[(wr + m * 16 + fr) * 32 + kq];
    }
#pragma unroll
    for (int n = 0; n < 4; ++n) {
      bfm[n] = *(const bf16x8*)&shB[(wc + n * 16 + fr) * 32 + kq];
      if constexpr (SPLIT)
        bfl[n] = *(const bf16x8*)&shBl[(wc + n * 16 + fr) * 32 + kq];
    }
#pragma unroll
    for (int m = 0; m < 4; ++m)
#pragma unroll
      for (int n = 0; n < 4; ++n) {
        acc[m][n] = __builtin_amdgcn_mfma_f32_16x16x32_bf16(af[m], bfm[n],
                                                            acc[m][n], 0, 0, 0);
        if constexpr (SPLIT) {
          acc[m][n] = __builtin_amdgcn_mfma_f32_16x16x32_bf16(
              af[m], bfl[n], acc[m][n], 0, 0, 0);
          acc[m][n] = __builtin_amdgcn_mfma_f32_16x16x32_bf16(
              afl[m], bfm[n], acc[m][n], 0, 0, 0);
        }
      }
    __syncthreads();
    if (ks + 1 < nk) stage((ks + 1) * 32);
  }

  // epilogue: C/D layout col = lane&15, row = (lane>>4)*4 + j  [m89-verified]
  int r0 = row0 + wr + (lane >> 4) * 4;
  int c0 = col0 + wc + fr;
  if constexpr (EPI == 0) {
    float* C = (float*)Cv + (long)z * sC;
#pragma unroll
    for (int m = 0; m < 4; ++m)
#pragma unroll
      for (int n = 0; n < 4; ++n)
#pragma unroll
        for (int j = 0; j < 4; ++j)
          C[(long)(r0 + m * 16 + j) * N + c0 + n * 16] = acc[m][n][j];
  } else if constexpr (EPI == 1) {
    bf16* C = (bf16*)Cv + (long)z * sC;
#pragma unroll
    for (int m = 0; m < 4; ++m)
#pragma unroll
      for (int n = 0; n < 4; ++n)
#pragma unroll
        for (int j = 0; j < 4; ++j)
          C[(long)(r0 + m * 16 + j) * N + c0 + n * 16] = (bf16)acc[m][n][j];
  } else {
    float* C = (float*)Cv;
#pragma unroll
    for (int n = 0; n < 4; ++n) {
      float bv = bias[c0 + n * 16];
#pragma unroll
      for (int m = 0; m < 4; ++m)
#pragma unroll
        for (int j = 0; j < 4; ++j) {
          float v = acc[m][n][j] + bv;
          C[(long)(r0 + m * 16 + j) * N + c0 + n * 16] = fmaxf(v, 0.f);
        }
    }
  }
}

extern "C" void kernel_launch(void* const* d_in, const int* in_sizes, int n_in,
                              void* d_out, int out_size, void* d_ws,
                              size_t ws_size, hipStream_t stream) {
  const float* passage = (const float*)d_in[0];
  const float* question = (const float*)d_in[1];
  const int* qmask = (const int*)d_in[2];
  const float* mapW = (const float*)d_in[3];
  const float* mapb = (const float*)d_in[4];

  char* ws = (char*)d_ws;
  size_t off = 0;
  auto alloc = [&](size_t bytes) {
    void* p = ws + off;
    off += (bytes + 255) & ~(size_t)255;
    return p;
  };
  // ~122 MB total; p_lo region reused for alpha, S region reused for O.
  bf16* p_hi = (bf16*)alloc((size_t)B_ * P_ * H_ * 2);
  bf16* p_lo = (bf16*)alloc((size_t)B_ * P_ * H_ * 2);
  bf16* q_hi = (bf16*)alloc((size_t)B_ * Q_ * H_ * 2);
  bf16* q_lo = (bf16*)alloc((size_t)B_ * Q_ * H_ * 2);
  bf16* qT = (bf16*)alloc((size_t)B_ * H_ * Q_ * 2);
  bf16* w_bf = (bf16*)alloc((size_t)H_ * H_ * 2);
  float* S = (float*)alloc((size_t)B_ * P_ * Q_ * 4);
  bf16* alpha = (bf16*)p_lo;  // p_lo dead after GEMM1
  bf16* O = (bf16*)S;         // S dead after softmax

  k_split<<<2048, 256, 0, stream>>>(passage, p_hi, p_lo, B_ * P_ * H_ / 4);
  k_split<<<1024, 256, 0, stream>>>(question, q_hi, q_lo, B_ * Q_ * H_ / 4);
  k_cvt<<<512, 256, 0, stream>>>(mapW, w_bf, H_ * H_ / 4);
  k_transpose<<<dim3(H_ / 64, Q_ / 64, B_), 256, 0, stream>>>(question, qT);

  // S = passage @ question^T  (split precision)
  k_gemm_bt<true, 0><<<dim3(Q_ / 128, P_ / 128, B_), 256, 0, stream>>>(
      p_hi, p_lo, q_hi, q_lo, S, nullptr, P_, Q_, H_, P_ * H_, Q_ * H_,
      P_ * Q_);

  k_softmax<<<B_ * P_ / 4, 256, 0, stream>>>(S, qmask, alpha);

  // O = alpha @ question  (B-operand = qT [H,Q])
  k_gemm_bt<false, 1><<<dim3(H_ / 128, P_ / 128, B_), 256, 0, stream>>>(
      alpha, nullptr, qT, nullptr, O, nullptr, P_, H_, Q_, P_ * Q_, H_ * Q_,
      P_ * H_);

  // Y = relu(O @ W^T + b)
  k_gemm_bt<false, 2><<<dim3(H_ / 128, (B_ * P_) / 128, 1), 256, 0, stream>>>(
      O, nullptr, w_bf, nullptr, d_out, mapb, B_ * P_, H_, H_, 0, 0, 0);
}

// Round 2
// 189.584 us; speedup vs baseline: 1.0937x; 1.0937x over previous
//
#include <hip/hip_runtime.h>
#include <hip/hip_bf16.h>

typedef __bf16 bf16;
typedef __bf16 bf16x8 __attribute__((ext_vector_type(8)));
typedef __bf16 bf16x4 __attribute__((ext_vector_type(4)));
typedef float  f32x4  __attribute__((ext_vector_type(4)));
typedef int    i32x4  __attribute__((ext_vector_type(4)));

#define B_ 8
#define P_ 2048
#define Q_ 512
#define H_ 1024

__device__ __forceinline__ void gload_lds16(const void* g, void* l) {
  __builtin_amdgcn_global_load_lds(
      (const __attribute__((address_space(1))) void*)g,
      (__attribute__((address_space(3))) void*)l, 16, 0, 0);
}

// ---- f32 -> bf16 hi/lo split (exact: hi+lo error ~2^-17 rel) ----
__global__ __launch_bounds__(256) void k_split(const float* __restrict__ x,
                                               bf16* __restrict__ hi,
                                               bf16* __restrict__ lo, int n4) {
  int i = blockIdx.x * blockDim.x + threadIdx.x;
  int stride = gridDim.x * blockDim.x;
  for (; i < n4; i += stride) {
    f32x4 v = ((const f32x4*)x)[i];
    bf16x4 h, l;
#pragma unroll
    for (int j = 0; j < 4; ++j) {
      bf16 hj = (bf16)v[j];
      h[j] = hj;
      l[j] = (bf16)(v[j] - (float)hj);
    }
    ((bf16x4*)hi)[i] = h;
    ((bf16x4*)lo)[i] = l;
  }
}

__global__ __launch_bounds__(256) void k_cvt(const float* __restrict__ x,
                                             bf16* __restrict__ y, int n4) {
  int i = blockIdx.x * blockDim.x + threadIdx.x;
  int stride = gridDim.x * blockDim.x;
  for (; i < n4; i += stride) {
    f32x4 v = ((const f32x4*)x)[i];
    bf16x4 h;
#pragma unroll
    for (int j = 0; j < 4; ++j) h[j] = (bf16)v[j];
    ((bf16x4*)y)[i] = h;
  }
}

// ---- question [B,Q,H] f32 -> qT [B,H,Q] bf16 (64x64 LDS tile) ----
__global__ __launch_bounds__(256) void k_transpose(const float* __restrict__ q,
                                                   bf16* __restrict__ qT) {
  __shared__ float t[64][65];
  int b = blockIdx.z;
  int h0 = blockIdx.x * 64, q0 = blockIdx.y * 64;
  int tid = threadIdx.x;
  int c4 = (tid & 15) * 4;
  int r16 = tid >> 4;
  const float* src = q + ((long)b * Q_ + q0) * H_ + h0;
#pragma unroll
  for (int i = 0; i < 4; ++i) {
    int r = r16 + i * 16;
    f32x4 v = *(const f32x4*)(src + (long)r * H_ + c4);
    t[c4 + 0][r] = v[0];
    t[c4 + 1][r] = v[1];
    t[c4 + 2][r] = v[2];
    t[c4 + 3][r] = v[3];
  }
  __syncthreads();
  bf16* dst = qT + ((long)b * H_ + h0) * Q_ + q0;
#pragma unroll
  for (int i = 0; i < 4; ++i) {
    int hr = r16 + i * 16;
    bf16x4 o;
#pragma unroll
    for (int j = 0; j < 4; ++j) o[j] = (bf16)t[hr][c4 + j];
    *(bf16x4*)(dst + (long)hr * Q_ + c4) = o;
  }
}

// ---- masked softmax: alpha_q = m*e^{t-c} / (Sum(m*e) + 1e-13*Z), one wave/row ----
__global__ __launch_bounds__(256) void k_softmax(const float* __restrict__ S,
                                                 const int* __restrict__ qmask,
                                                 bf16* __restrict__ alpha) {
  int row = blockIdx.x * 4 + (threadIdx.x >> 6);
  int lane = threadIdx.x & 63;
  int b = row >> 11;  // P_=2048 rows per batch
  const float* s = S + (long)row * Q_;
  const int* mp = qmask + b * Q_;
  f32x4 v0 = ((const f32x4*)s)[lane * 2];
  f32x4 v1 = ((const f32x4*)s)[lane * 2 + 1];
  i32x4 m0 = ((const i32x4*)mp)[lane * 2];
  i32x4 m1 = ((const i32x4*)mp)[lane * 2 + 1];
  float t[8], mf[8];
#pragma unroll
  for (int j = 0; j < 4; ++j) {
    mf[j] = (float)m0[j];     t[j] = v0[j] * mf[j];
    mf[4 + j] = (float)m1[j]; t[4 + j] = v1[j] * mf[4 + j];
  }
  float mx = t[0];
#pragma unroll
  for (int j = 1; j < 8; ++j) mx = fmaxf(mx, t[j]);
  for (int o = 32; o; o >>= 1) mx = fmaxf(mx, __shfl_xor(mx, o, 64));
  float e[8], Z = 0.f, Sm = 0.f;
#pragma unroll
  for (int j = 0; j < 8; ++j) {
    e[j] = expf(t[j] - mx);
    Z += e[j];
    Sm += e[j] * mf[j];
  }
  for (int o = 32; o; o >>= 1) {
    Z += __shfl_xor(Z, o, 64);
    Sm += __shfl_xor(Sm, o, 64);
  }
  float inv = 1.0f / (Sm + 1e-13f * Z);
  bf16x8 out;
#pragma unroll
  for (int j = 0; j < 8; ++j) out[j] = (bf16)(e[j] * mf[j] * inv);
  *(bf16x8*)(alpha + (long)row * Q_ + lane * 8) = out;
}

// ---- m97-style 128x128 bf16 GEMM, A[M,K] * B[N,K]^T, BK=32, 4 waves ----
// XCD-aware bijective block swizzle (T1, m204): contiguous logical chunk per XCD.
// SPLIT: 3-MFMA hi/lo split accumulation (f32-class precision for scores)
// EPI: 0 = f32 store, 1 = bf16 store, 2 = f32 bias+relu store
template <bool SPLIT, int EPI>
__global__ __launch_bounds__(256) void k_gemm_bt(
    const bf16* __restrict__ A, const bf16* __restrict__ Al,
    const bf16* __restrict__ Bm, const bf16* __restrict__ Bl,
    void* __restrict__ Cv, const float* __restrict__ bias,
    int M, int N, int K, int sA, int sB, int sC) {
  __shared__ __align__(16) bf16 smem[(SPLIT ? 4 : 2) * 4096];
  bf16* shA = smem;
  bf16* shB = smem + 4096;
  bf16* shAl = SPLIT ? smem + 8192 : nullptr;
  bf16* shBl = SPLIT ? smem + 12288 : nullptr;

  // --- XCD swizzle: hw id round-robins XCDs (orig&7 = XCD); give each XCD a
  // contiguous logical chunk so column-blocks sharing an A-panel stay in one L2.
  int gx = gridDim.x, gy = gridDim.y;
  int nwg = gx * gy * (int)gridDim.z;  // all our grids: nwg % 8 == 0
  int orig = blockIdx.x + gx * (blockIdx.y + gy * blockIdx.z);
  int wg = (orig & 7) * (nwg >> 3) + (orig >> 3);
  int bx = wg % gx;
  int t2 = wg / gx;
  int by = t2 % gy;
  int z = t2 / gy;

  int tid = threadIdx.x, wv = tid >> 6, lane = tid & 63;
  A += (long)z * sA;
  Bm += (long)z * sB;
  if constexpr (SPLIT) {
    Al += (long)z * sA;
    Bl += (long)z * sB;
  }
  int row0 = by * 128, col0 = bx * 128;

  auto stage = [&](int k0) {
    int gr = tid >> 2;
    int gc = (tid & 3) * 8;
#pragma unroll
    for (int i = 0; i < 2; ++i) {
      long aoff = (long)(row0 + i * 64 + gr) * K + k0 + gc;
      long boff = (long)(col0 + i * 64 + gr) * K + k0 + gc;
      int loff = i * 2048 + wv * 512;  // wave-uniform LDS base (elements)
      gload_lds16(A + aoff, shA + loff);
      gload_lds16(Bm + boff, shB + loff);
      if constexpr (SPLIT) {
        gload_lds16(Al + aoff, shAl + loff);
        gload_lds16(Bl + boff, shBl + loff);
      }
    }
  };

  f32x4 acc[4][4] = {};
  stage(0);
  int nk = K / 32;
  int wr = (wv >> 1) * 64, wc = (wv & 1) * 64;
  int fr = lane & 15, kq = (lane >> 4) * 8;
  for (int ks = 0; ks < nk; ++ks) {
    __syncthreads();
    bf16x8 af[4], bfm[4], afl[4], bfl[4];
#pragma unroll
    for (int m = 0; m < 4; ++m) {
      af[m] = *(const bf16x8*)&shA[(wr + m * 16 + fr) * 32 + kq];
      if constexpr (SPLIT)
        afl[m] = *(const bf16x8*)&shAl[(wr + m * 16 + fr) * 32 + kq];
    }
#pragma unroll
    for (int n = 0; n < 4; ++n) {
      bfm[n] = *(const bf16x8*)&shB[(wc + n * 16 + fr) * 32 + kq];
      if constexpr (SPLIT)
        bfl[n] = *(const bf16x8*)&shBl[(wc + n * 16 + fr) * 32 + kq];
    }
#pragma unroll
    for (int m = 0; m < 4; ++m)
#pragma unroll
      for (int n = 0; n < 4; ++n) {
        acc[m][n] = __builtin_amdgcn_mfma_f32_16x16x32_bf16(af[m], bfm[n],
                                                            acc[m][n], 0, 0, 0);
        if constexpr (SPLIT) {
          acc[m][n] = __builtin_amdgcn_mfma_f32_16x16x32_bf16(
              af[m], bfl[n], acc[m][n], 0, 0, 0);
          acc[m][n] = __builtin_amdgcn_mfma_f32_16x16x32_bf16(
              afl[m], bfm[n], acc[m][n], 0, 0, 0);
        }
      }
    __syncthreads();
    if (ks + 1 < nk) stage((ks + 1) * 32);
  }

  // epilogue: C/D layout col = lane&15, row = (lane>>4)*4 + j  [m89-verified]
  int r0 = row0 + wr + (lane >> 4) * 4;
  int c0 = col0 + wc + fr;
  if constexpr (EPI == 0) {
    float* C = (float*)Cv + (long)z * sC;
#pragma unroll
    for (int m = 0; m < 4; ++m)
#pragma unroll
      for (int n = 0; n < 4; ++n)
#pragma unroll
        for (int j = 0; j < 4; ++j)
          C[(long)(r0 + m * 16 + j) * N + c0 + n * 16] = acc[m][n][j];
  } else if constexpr (EPI == 1) {
    bf16* C = (bf16*)Cv + (long)z * sC;
#pragma unroll
    for (int m = 0; m < 4; ++m)
#pragma unroll
      for (int n = 0; n < 4; ++n)
#pragma unroll
        for (int j = 0; j < 4; ++j)
          C[(long)(r0 + m * 16 + j) * N + c0 + n * 16] = (bf16)acc[m][n][j];
  } else {
    float* C = (float*)Cv;
#pragma unroll
    for (int n = 0; n < 4; ++n) {
      float bv = bias[c0 + n * 16];
#pragma unroll
      for (int m = 0; m < 4; ++m)
#pragma unroll
        for (int j = 0; j < 4; ++j) {
          float v = acc[m][n][j] + bv;
          C[(long)(r0 + m * 16 + j) * N + c0 + n * 16] = fmaxf(v, 0.f);
        }
    }
  }
}

extern "C" void kernel_launch(void* const* d_in, const int* in_sizes, int n_in,
                              void* d_out, int out_size, void* d_ws,
                              size_t ws_size, hipStream_t stream) {
  const float* passage = (const float*)d_in[0];
  const float* question = (const float*)d_in[1];
  const int* qmask = (const int*)d_in[2];
  const float* mapW = (const float*)d_in[3];
  const float* mapb = (const float*)d_in[4];

  char* ws = (char*)d_ws;
  size_t off = 0;
  auto alloc = [&](size_t bytes) {
    void* p = ws + off;
    off += (bytes + 255) & ~(size_t)255;
    return p;
  };
  // ~122 MB total; p_lo region reused for alpha, S region reused for O.
  bf16* p_hi = (bf16*)alloc((size_t)B_ * P_ * H_ * 2);
  bf16* p_lo = (bf16*)alloc((size_t)B_ * P_ * H_ * 2);
  bf16* q_hi = (bf16*)alloc((size_t)B_ * Q_ * H_ * 2);
  bf16* q_lo = (bf16*)alloc((size_t)B_ * Q_ * H_ * 2);
  bf16* qT = (bf16*)alloc((size_t)B_ * H_ * Q_ * 2);
  bf16* w_bf = (bf16*)alloc((size_t)H_ * H_ * 2);
  float* S = (float*)alloc((size_t)B_ * P_ * Q_ * 4);
  bf16* alpha = (bf16*)p_lo;  // p_lo dead after GEMM1
  bf16* O = (bf16*)S;         // S dead after softmax

  k_split<<<2048, 256, 0, stream>>>(passage, p_hi, p_lo, B_ * P_ * H_ / 4);
  k_split<<<1024, 256, 0, stream>>>(question, q_hi, q_lo, B_ * Q_ * H_ / 4);
  k_cvt<<<512, 256, 0, stream>>>(mapW, w_bf, H_ * H_ / 4);
  k_transpose<<<dim3(H_ / 64, Q_ / 64, B_), 256, 0, stream>>>(question, qT);

  // S = passage @ question^T  (split precision)
  k_gemm_bt<true, 0><<<dim3(Q_ / 128, P_ / 128, B_), 256, 0, stream>>>(
      p_hi, p_lo, q_hi, q_lo, S, nullptr, P_, Q_, H_, P_ * H_, Q_ * H_,
      P_ * Q_);

  k_softmax<<<B_ * P_ / 4, 256, 0, stream>>>(S, qmask, alpha);

  // O = alpha @ question  (B-operand = qT [H,Q])
  k_gemm_bt<false, 1><<<dim3(H_ / 128, P_ / 128, B_), 256, 0, stream>>>(
      alpha, nullptr, qT, nullptr, O, nullptr, P_, H_, Q_, P_ * Q_, H_ * Q_,
      P_ * H_);

  // Y = relu(O @ W^T + b)
  k_gemm_bt<false, 2><<<dim3(H_ / 128, (B_ * P_) / 128, 1), 256, 0, stream>>>(
      O, nullptr, w_bf, nullptr, d_out, mapb, B_ * P_, H_, H_, 0, 0, 0);
}

// Round 3
// 163.561 us; speedup vs baseline: 1.2677x; 1.1591x over previous
//
#include <hip/hip_runtime.h>
#include <hip/hip_bf16.h>

typedef __bf16 bf16;
typedef __bf16 bf16x8 __attribute__((ext_vector_type(8)));
typedef __bf16 bf16x4 __attribute__((ext_vector_type(4)));
typedef float  f32x4  __attribute__((ext_vector_type(4)));
typedef int    i32x4  __attribute__((ext_vector_type(4)));

#define B_ 8
#define P_ 2048
#define Q_ 512
#define H_ 1024

__device__ __forceinline__ void gload_lds16(const void* g, void* l) {
  __builtin_amdgcn_global_load_lds(
      (const __attribute__((address_space(1))) void*)g,
      (__attribute__((address_space(3))) void*)l, 16, 0, 0);
}

// ---- f32 -> bf16 hi/lo split (exact: hi+lo error ~2^-17 rel) ----
__global__ __launch_bounds__(256) void k_split(const float* __restrict__ x,
                                               bf16* __restrict__ hi,
                                               bf16* __restrict__ lo, int n4) {
  int i = blockIdx.x * blockDim.x + threadIdx.x;
  int stride = gridDim.x * blockDim.x;
  for (; i < n4; i += stride) {
    f32x4 v = ((const f32x4*)x)[i];
    bf16x4 h, l;
#pragma unroll
    for (int j = 0; j < 4; ++j) {
      bf16 hj = (bf16)v[j];
      h[j] = hj;
      l[j] = (bf16)(v[j] - (float)hj);
    }
    ((bf16x4*)hi)[i] = h;
    ((bf16x4*)lo)[i] = l;
  }
}

__global__ __launch_bounds__(256) void k_cvt(const float* __restrict__ x,
                                             bf16* __restrict__ y, int n4) {
  int i = blockIdx.x * blockDim.x + threadIdx.x;
  int stride = gridDim.x * blockDim.x;
  for (; i < n4; i += stride) {
    f32x4 v = ((const f32x4*)x)[i];
    bf16x4 h;
#pragma unroll
    for (int j = 0; j < 4; ++j) h[j] = (bf16)v[j];
    ((bf16x4*)y)[i] = h;
  }
}

// ---- question [B,Q,H] f32 -> qT [B,H,Q] bf16 (64x64 LDS tile) ----
__global__ __launch_bounds__(256) void k_transpose(const float* __restrict__ q,
                                                   bf16* __restrict__ qT) {
  __shared__ float t[64][65];
  int b = blockIdx.z;
  int h0 = blockIdx.x * 64, q0 = blockIdx.y * 64;
  int tid = threadIdx.x;
  int c4 = (tid & 15) * 4;
  int r16 = tid >> 4;
  const float* src = q + ((long)b * Q_ + q0) * H_ + h0;
#pragma unroll
  for (int i = 0; i < 4; ++i) {
    int r = r16 + i * 16;
    f32x4 v = *(const f32x4*)(src + (long)r * H_ + c4);
    t[c4 + 0][r] = v[0];
    t[c4 + 1][r] = v[1];
    t[c4 + 2][r] = v[2];
    t[c4 + 3][r] = v[3];
  }
  __syncthreads();
  bf16* dst = qT + ((long)b * H_ + h0) * Q_ + q0;
#pragma unroll
  for (int i = 0; i < 4; ++i) {
    int hr = r16 + i * 16;
    bf16x4 o;
#pragma unroll
    for (int j = 0; j < 4; ++j) o[j] = (bf16)t[hr][c4 + j];
    *(bf16x4*)(dst + (long)hr * Q_ + c4) = o;
  }
}

// ---- masked softmax: alpha_q = m*e^{t-c} / (Sum(m*e) + 1e-13*Z), one wave/row ----
__global__ __launch_bounds__(256) void k_softmax(const float* __restrict__ S,
                                                 const int* __restrict__ qmask,
                                                 bf16* __restrict__ alpha) {
  int row = blockIdx.x * 4 + (threadIdx.x >> 6);
  int lane = threadIdx.x & 63;
  int b = row >> 11;  // P_=2048 rows per batch
  const float* s = S + (long)row * Q_;
  const int* mp = qmask + b * Q_;
  f32x4 v0 = ((const f32x4*)s)[lane * 2];
  f32x4 v1 = ((const f32x4*)s)[lane * 2 + 1];
  i32x4 m0 = ((const i32x4*)mp)[lane * 2];
  i32x4 m1 = ((const i32x4*)mp)[lane * 2 + 1];
  float t[8], mf[8];
#pragma unroll
  for (int j = 0; j < 4; ++j) {
    mf[j] = (float)m0[j];     t[j] = v0[j] * mf[j];
    mf[4 + j] = (float)m1[j]; t[4 + j] = v1[j] * mf[4 + j];
  }
  float mx = t[0];
#pragma unroll
  for (int j = 1; j < 8; ++j) mx = fmaxf(mx, t[j]);
  for (int o = 32; o; o >>= 1) mx = fmaxf(mx, __shfl_xor(mx, o, 64));
  float e[8], Z = 0.f, Sm = 0.f;
#pragma unroll
  for (int j = 0; j < 8; ++j) {
    e[j] = expf(t[j] - mx);
    Z += e[j];
    Sm += e[j] * mf[j];
  }
  for (int o = 32; o; o >>= 1) {
    Z += __shfl_xor(Z, o, 64);
    Sm += __shfl_xor(Sm, o, 64);
  }
  float inv = 1.0f / (Sm + 1e-13f * Z);
  bf16x8 out;
#pragma unroll
  for (int j = 0; j < 8; ++j) out[j] = (bf16)(e[j] * mf[j] * inv);
  *(bf16x8*)(alpha + (long)row * Q_ + lane * 8) = out;
}

// ---- split-precision 128x128 GEMM (m97 structure) — GEMM1 only ----
template <bool SPLIT, int EPI>
__global__ __launch_bounds__(256) void k_gemm_bt(
    const bf16* __restrict__ A, const bf16* __restrict__ Al,
    const bf16* __restrict__ Bm, const bf16* __restrict__ Bl,
    void* __restrict__ Cv, const float* __restrict__ bias,
    int M, int N, int K, int sA, int sB, int sC) {
  __shared__ __align__(16) bf16 smem[(SPLIT ? 4 : 2) * 4096];
  bf16* shA = smem;
  bf16* shB = smem + 4096;
  bf16* shAl = SPLIT ? smem + 8192 : nullptr;
  bf16* shBl = SPLIT ? smem + 12288 : nullptr;

  int gx = gridDim.x, gy = gridDim.y;
  int nwg = gx * gy * (int)gridDim.z;
  int orig = blockIdx.x + gx * (blockIdx.y + gy * blockIdx.z);
  int wg = (orig & 7) * (nwg >> 3) + (orig >> 3);
  int bx = wg % gx;
  int t2 = wg / gx;
  int by = t2 % gy;
  int z = t2 / gy;

  int tid = threadIdx.x, wv = tid >> 6, lane = tid & 63;
  A += (long)z * sA;
  Bm += (long)z * sB;
  if constexpr (SPLIT) {
    Al += (long)z * sA;
    Bl += (long)z * sB;
  }
  int row0 = by * 128, col0 = bx * 128;

  auto stage = [&](int k0) {
    int gr = tid >> 2;
    int gc = (tid & 3) * 8;
#pragma unroll
    for (int i = 0; i < 2; ++i) {
      long aoff = (long)(row0 + i * 64 + gr) * K + k0 + gc;
      long boff = (long)(col0 + i * 64 + gr) * K + k0 + gc;
      int loff = i * 2048 + wv * 512;
      gload_lds16(A + aoff, shA + loff);
      gload_lds16(Bm + boff, shB + loff);
      if constexpr (SPLIT) {
        gload_lds16(Al + aoff, shAl + loff);
        gload_lds16(Bl + boff, shBl + loff);
      }
    }
  };

  f32x4 acc[4][4] = {};
  stage(0);
  int nk = K / 32;
  int wr = (wv >> 1) * 64, wc = (wv & 1) * 64;
  int fr = lane & 15, kq = (lane >> 4) * 8;
  for (int ks = 0; ks < nk; ++ks) {
    __syncthreads();
    bf16x8 af[4], bfm[4], afl[4], bfl[4];
#pragma unroll
    for (int m = 0; m < 4; ++m) {
      af[m] = *(const bf16x8*)&shA[(wr + m * 16 + fr) * 32 + kq];
      if constexpr (SPLIT)
        afl[m] = *(const bf16x8*)&shAl[(wr + m * 16 + fr) * 32 + kq];
    }
#pragma unroll
    for (int n = 0; n < 4; ++n) {
      bfm[n] = *(const bf16x8*)&shB[(wc + n * 16 + fr) * 32 + kq];
      if constexpr (SPLIT)
        bfl[n] = *(const bf16x8*)&shBl[(wc + n * 16 + fr) * 32 + kq];
    }
#pragma unroll
    for (int m = 0; m < 4; ++m)
#pragma unroll
      for (int n = 0; n < 4; ++n) {
        acc[m][n] = __builtin_amdgcn_mfma_f32_16x16x32_bf16(af[m], bfm[n],
                                                            acc[m][n], 0, 0, 0);
        if constexpr (SPLIT) {
          acc[m][n] = __builtin_amdgcn_mfma_f32_16x16x32_bf16(
              af[m], bfl[n], acc[m][n], 0, 0, 0);
          acc[m][n] = __builtin_amdgcn_mfma_f32_16x16x32_bf16(
              afl[m], bfm[n], acc[m][n], 0, 0, 0);
        }
      }
    __syncthreads();
    if (ks + 1 < nk) stage((ks + 1) * 32);
  }

  int r0 = row0 + wr + (lane >> 4) * 4;
  int c0 = col0 + wc + fr;
  if constexpr (EPI == 0) {
    float* C = (float*)Cv + (long)z * sC;
#pragma unroll
    for (int m = 0; m < 4; ++m)
#pragma unroll
      for (int n = 0; n < 4; ++n)
#pragma unroll
        for (int j = 0; j < 4; ++j)
          C[(long)(r0 + m * 16 + j) * N + c0 + n * 16] = acc[m][n][j];
  }
}

// ---- 256x256-tile deep-pipelined GEMM (T3/T4): A[M,K] * B[N,K]^T ----
// 512 thr / 8 waves (2Mx4N), per-wave 128x64 out. BK=32, 4-buffer LDS ring
// (128 KiB), prefetch distance 3, counted vmcnt(8) across raw s_barrier.
// LDS chunk swizzle c^=(row>>1)&3 (inverse-perm on global source, rule 21)
// -> each 8-lane beat of ds_read_b128 hits 8 distinct bank quads.
// EPI: 1 = bf16 store, 2 = f32 bias+relu store.
template <int EPI, int NT>
__global__ __launch_bounds__(512, 2) void k_gemm256(
    const bf16* __restrict__ A, const bf16* __restrict__ Bm,
    void* __restrict__ Cv, const float* __restrict__ bias, int N, int gx,
    int gy, long sA, long sB, long sC) {
  constexpr int K = NT * 32;
  __shared__ __align__(16) bf16 smem[65536];  // 4 bufs x (A 8192 + B 8192)

  int nwg = gridDim.x;  // 256, multiple of 8
  int orig = blockIdx.x;
  int wg = (orig & 7) * (nwg >> 3) + (orig >> 3);  // T1 bijective
  int bx = wg % gx;
  int tt = wg / gx;
  int by = tt % gy;
  int z = tt / gy;
  int row0 = by * 256, col0 = bx * 256;
  A += z * sA;
  Bm += z * sB;

  int tid = threadIdx.x, wv = tid >> 6, lane = tid & 63;

  // --- staging constants: waves 0-3 stage A (units 0-15), 4-7 stage B ---
  bool isA = wv < 4;
  int u0 = (wv & 3) * 4;                           // first unit (of 16)
  int srow = u0 * 16 + (lane >> 2);                // unit = 16 rows of 64B
  int sclog = ((lane & 3) ^ ((lane >> 3) & 3)) * 8;  // pre-swizzled chunk
  const bf16* sbaseG = isA ? A + (long)(row0 + srow) * K + sclog
                           : Bm + (long)(col0 + srow) * K + sclog;
  int sbaseL = (isA ? 0 : 8192) + u0 * 512;  // wave-uniform LDS elem offset

  auto stage = [&](int tile) {
    const bf16* g = sbaseG + tile * 32;
    bf16* l = smem + (tile & 3) * 16384 + sbaseL;
#pragma unroll
    for (int j = 0; j < 4; ++j) gload_lds16(g + (long)j * 16 * K, l + j * 512);
  };

  // --- fragment constants ---
  int wr = (wv >> 2) * 128, wc = (wv & 3) * 64;
  int fr = lane & 15, kq = lane >> 4;
  int swz = (kq ^ ((fr >> 1) & 3)) * 8 + fr * 32;  // per-lane, frag-invariant

  f32x4 acc[8][4] = {};
  auto compute = [&](int t) {
    const bf16* bufA = smem + (t & 3) * 16384;
    const bf16* bufB = bufA + 8192;
    bf16x8 af[8], bfr[4];
#pragma unroll
    for (int m = 0; m < 8; ++m)
      af[m] = *(const bf16x8*)(bufA + (wr + m * 16) * 32 + swz);
#pragma unroll
    for (int n = 0; n < 4; ++n)
      bfr[n] = *(const bf16x8*)(bufB + (wc + n * 16) * 32 + swz);
#pragma unroll
    for (int m = 0; m < 8; ++m)
#pragma unroll
      for (int n = 0; n < 4; ++n)
        acc[m][n] = __builtin_amdgcn_mfma_f32_16x16x32_bf16(af[m], bfr[n],
                                                            acc[m][n], 0, 0, 0);
  };

  stage(0);
  stage(1);
  stage(2);
  asm volatile("s_waitcnt vmcnt(8)" ::: "memory");  // tile 0 landed
  __builtin_amdgcn_s_barrier();
  __builtin_amdgcn_sched_barrier(0);
  for (int t = 0; t < NT - 3; ++t) {
    stage(t + 3);  // issue early; hides under MFMA
    compute(t);
    asm volatile("s_waitcnt vmcnt(8)" ::: "memory");  // t+1 landed; 8 in flight
    __builtin_amdgcn_s_barrier();
    __builtin_amdgcn_sched_barrier(0);
  }
  compute(NT - 3);
  asm volatile("s_waitcnt vmcnt(4)" ::: "memory");
  __builtin_amdgcn_s_barrier();
  __builtin_amdgcn_sched_barrier(0);
  compute(NT - 2);
  asm volatile("s_waitcnt vmcnt(0)" ::: "memory");
  __builtin_amdgcn_s_barrier();
  __builtin_amdgcn_sched_barrier(0);
  compute(NT - 1);

  // epilogue: C/D layout col = lane&15, row = (lane>>4)*4 + j
  int r0 = row0 + wr + (lane >> 4) * 4;
  int c0 = col0 + wc + fr;
  if constexpr (EPI == 1) {
    bf16* C = (bf16*)Cv + z * sC;
#pragma unroll
    for (int m = 0; m < 8; ++m)
#pragma unroll
      for (int n = 0; n < 4; ++n)
#pragma unroll
        for (int j = 0; j < 4; ++j)
          C[(long)(r0 + m * 16 + j) * N + c0 + n * 16] = (bf16)acc[m][n][j];
  } else {
    float* C = (float*)Cv;
#pragma unroll
    for (int n = 0; n < 4; ++n) {
      float bv = bias[c0 + n * 16];
#pragma unroll
      for (int m = 0; m < 8; ++m)
#pragma unroll
        for (int j = 0; j < 4; ++j) {
          float v = acc[m][n][j] + bv;
          C[(long)(r0 + m * 16 + j) * N + c0 + n * 16] = fmaxf(v, 0.f);
        }
    }
  }
}

extern "C" void kernel_launch(void* const* d_in, const int* in_sizes, int n_in,
                              void* d_out, int out_size, void* d_ws,
                              size_t ws_size, hipStream_t stream) {
  const float* passage = (const float*)d_in[0];
  const float* question = (const float*)d_in[1];
  const int* qmask = (const int*)d_in[2];
  const float* mapW = (const float*)d_in[3];
  const float* mapb = (const float*)d_in[4];

  char* ws = (char*)d_ws;
  size_t off = 0;
  auto alloc = [&](size_t bytes) {
    void* p = ws + off;
    off += (bytes + 255) & ~(size_t)255;
    return p;
  };
  bf16* p_hi = (bf16*)alloc((size_t)B_ * P_ * H_ * 2);
  bf16* p_lo = (bf16*)alloc((size_t)B_ * P_ * H_ * 2);
  bf16* q_hi = (bf16*)alloc((size_t)B_ * Q_ * H_ * 2);
  bf16* q_lo = (bf16*)alloc((size_t)B_ * Q_ * H_ * 2);
  bf16* qT = (bf16*)alloc((size_t)B_ * H_ * Q_ * 2);
  bf16* w_bf = (bf16*)alloc((size_t)H_ * H_ * 2);
  float* S = (float*)alloc((size_t)B_ * P_ * Q_ * 4);
  bf16* alpha = (bf16*)p_lo;  // p_lo dead after GEMM1
  bf16* O = (bf16*)S;         // S dead after softmax

  k_split<<<2048, 256, 0, stream>>>(passage, p_hi, p_lo, B_ * P_ * H_ / 4);
  k_split<<<1024, 256, 0, stream>>>(question, q_hi, q_lo, B_ * Q_ * H_ / 4);
  k_cvt<<<512, 256, 0, stream>>>(mapW, w_bf, H_ * H_ / 4);
  k_transpose<<<dim3(H_ / 64, Q_ / 64, B_), 256, 0, stream>>>(question, qT);

  // GEMM1: S = passage @ question^T  (split precision, m97 structure)
  k_gemm_bt<true, 0><<<dim3(Q_ / 128, P_ / 128, B_), 256, 0, stream>>>(
      p_hi, p_lo, q_hi, q_lo, S, nullptr, P_, Q_, H_, P_ * H_, Q_ * H_,
      P_ * Q_);

  k_softmax<<<B_ * P_ / 4, 256, 0, stream>>>(S, qmask, alpha);

  // GEMM3: O = alpha @ question  (B-operand = qT [H,Q]); 256 blocks, 1/XCD/batch
  k_gemm256<1, Q_ / 32><<<256, 512, 0, stream>>>(
      alpha, qT, O, nullptr, H_, H_ / 256, P_ / 256, (long)P_ * Q_,
      (long)H_ * Q_, (long)P_ * H_);

  // GEMM4: Y = relu(O @ W^T + b); 256 blocks
  k_gemm256<2, H_ / 32><<<256, 512, 0, stream>>>(
      O, w_bf, d_out, mapb, H_, H_ / 256, (B_ * P_) / 256, 0, 0, 0);
}

// Round 4
// 144.432 us; speedup vs baseline: 1.4357x; 1.1324x over previous
//
#include <hip/hip_runtime.h>
#include <hip/hip_bf16.h>

typedef __bf16 bf16;
typedef __bf16 bf16x8 __attribute__((ext_vector_type(8)));
typedef __bf16 bf16x4 __attribute__((ext_vector_type(4)));
typedef float  f32x4  __attribute__((ext_vector_type(4)));

#define B_ 8
#define P_ 2048
#define Q_ 512
#define H_ 1024

__device__ __forceinline__ void gload_lds16(const void* g, void* l) {
  __builtin_amdgcn_global_load_lds(
      (const __attribute__((address_space(1))) void*)g,
      (__attribute__((address_space(3))) void*)l, 16, 0, 0);
}

// ---- f32 -> bf16 hi/lo split (question only now) ----
__global__ __launch_bounds__(256) void k_split(const float* __restrict__ x,
                                               bf16* __restrict__ hi,
                                               bf16* __restrict__ lo, int n4) {
  int i = blockIdx.x * blockDim.x + threadIdx.x;
  int stride = gridDim.x * blockDim.x;
  for (; i < n4; i += stride) {
    f32x4 v = ((const f32x4*)x)[i];
    bf16x4 h, l;
#pragma unroll
    for (int j = 0; j < 4; ++j) {
      bf16 hj = (bf16)v[j];
      h[j] = hj;
      l[j] = (bf16)(v[j] - (float)hj);
    }
    ((bf16x4*)hi)[i] = h;
    ((bf16x4*)lo)[i] = l;
  }
}

__global__ __launch_bounds__(256) void k_cvt(const float* __restrict__ x,
                                             bf16* __restrict__ y, int n4) {
  int i = blockIdx.x * blockDim.x + threadIdx.x;
  int stride = gridDim.x * blockDim.x;
  for (; i < n4; i += stride) {
    f32x4 v = ((const f32x4*)x)[i];
    bf16x4 h;
#pragma unroll
    for (int j = 0; j < 4; ++j) h[j] = (bf16)v[j];
    ((bf16x4*)y)[i] = h;
  }
}

// ---- question [B,Q,H] f32 -> qT [B,H,Q] bf16 ----
__global__ __launch_bounds__(256) void k_transpose(const float* __restrict__ q,
                                                   bf16* __restrict__ qT) {
  __shared__ float t[64][65];
  int b = blockIdx.z;
  int h0 = blockIdx.x * 64, q0 = blockIdx.y * 64;
  int tid = threadIdx.x;
  int c4 = (tid & 15) * 4;
  int r16 = tid >> 4;
  const float* src = q + ((long)b * Q_ + q0) * H_ + h0;
#pragma unroll
  for (int i = 0; i < 4; ++i) {
    int r = r16 + i * 16;
    f32x4 v = *(const f32x4*)(src + (long)r * H_ + c4);
    t[c4 + 0][r] = v[0];
    t[c4 + 1][r] = v[1];
    t[c4 + 2][r] = v[2];
    t[c4 + 3][r] = v[3];
  }
  __syncthreads();
  bf16* dst = qT + ((long)b * H_ + h0) * Q_ + q0;
#pragma unroll
  for (int i = 0; i < 4; ++i) {
    int hr = r16 + i * 16;
    bf16x4 o;
#pragma unroll
    for (int j = 0; j < 4; ++j) o[j] = (bf16)t[hr][c4 + j];
    *(bf16x4*)(dst + (long)hr * Q_ + c4) = o;
  }
}

// ==== fused: S-tile (split-bf16, f32-class precision) + masked softmax ====
// Block = 64 rows x 512 cols (full Q). 512 thr / 8 waves (2M x 4N), wave tile
// 32x128. BK=32, 2-buffer LDS ring (147456 B). A (passage f32) reg-staged with
// in-kernel hi/lo split (kills the k_split passage round-trip); B (q_hi/q_lo)
// via global_load_lds with chunk-XOR swizzle pre-applied on the global source
// (rule 21). Epilogue: exact masked softmax, alpha = m*e^{t-c}/(Sm + 1e-13*Z).
__global__ __launch_bounds__(512) void k_score_softmax(
    const float* __restrict__ passage, const bf16* __restrict__ q_hi,
    const bf16* __restrict__ q_lo, const int* __restrict__ qmask,
    bf16* __restrict__ alpha) {
  constexpr int NT = H_ / 32;   // 32 K-tiles
  constexpr int BUF = 36864;    // elems per buffer: A 4096 (hi+lo) + B 32768
  __shared__ __align__(16) bf16 smem[2 * BUF];  // 147456 B

  int orig = blockIdx.x;      // 256 blocks
  int z = orig & 7;           // batch == XCD (T1): question L2-resident
  int row0 = (orig >> 3) * 64;

  int tid = threadIdx.x, wv = tid >> 6, lane = tid & 63;
  int fr = lane & 15;
  int kq = lane >> 4;
  int wr = (wv >> 2) * 32, wc = (wv & 3) * 128;
  int swz = (kq ^ ((fr >> 1) & 3)) * 8;

  // A staging: thread -> (row r=tid>>3 of 64, k-chunk (tid&7)*4)
  const float* gA =
      passage + ((long)(z * P_ + row0 + (tid >> 3))) * H_ + (tid & 7) * 4;
  int aw = (tid >> 3) * 32 + ((((tid & 7) >> 1) ^ ((tid >> 4) & 3)) * 8) +
           (tid & 1) * 4;  // swizzled LDS elem addr for A hi image
  // B staging: 4 lanes/row, chunk pre-swizzled on global source
  long broff = ((long)(z * Q_ + (tid >> 2))) * H_ +
               (((tid & 3) ^ ((tid >> 3) & 3)) * 8);
  const bf16* gBh = q_hi + broff;
  const bf16* gBl = q_lo + broff;
  int ldsBh = 4096 + wv * 512;
  int ldsBl = 20480 + wv * 512;

  auto stageB = [&](int t) {
    int bb = (t & 1) * BUF;
    const bf16* gh = gBh + t * 32;
    const bf16* gl = gBl + t * 32;
#pragma unroll
    for (int p = 0; p < 4; ++p)
      gload_lds16(gh + (long)p * 128 * H_, smem + bb + ldsBh + p * 4096);
#pragma unroll
    for (int p = 0; p < 4; ++p)
      gload_lds16(gl + (long)p * 128 * H_, smem + bb + ldsBl + p * 4096);
  };
  auto writeA = [&](int t, f32x4 av) {
    bf16x4 h, l;
#pragma unroll
    for (int j = 0; j < 4; ++j) {
      h[j] = (bf16)av[j];
      l[j] = (bf16)(av[j] - (float)h[j]);
    }
    int bb = (t & 1) * BUF;
    *(bf16x4*)(smem + bb + aw) = h;
    *(bf16x4*)(smem + bb + 2048 + aw) = l;
  };

  f32x4 acc[2][8] = {};
  auto compute = [&](int t) {
    const bf16* bb = smem + (t & 1) * BUF;
    bf16x8 ah[2], al[2], bh[8], bl[8];
#pragma unroll
    for (int m = 0; m < 2; ++m) {
      int ro = (wr + m * 16 + fr) * 32 + swz;
      ah[m] = *(const bf16x8*)(bb + ro);
      al[m] = *(const bf16x8*)(bb + 2048 + ro);
    }
#pragma unroll
    for (int n = 0; n < 8; ++n) {
      int ro = (wc + n * 16 + fr) * 32 + swz;
      bh[n] = *(const bf16x8*)(bb + 4096 + ro);
      bl[n] = *(const bf16x8*)(bb + 20480 + ro);
    }
#pragma unroll
    for (int m = 0; m < 2; ++m)
#pragma unroll
      for (int n = 0; n < 8; ++n) {
        acc[m][n] = __builtin_amdgcn_mfma_f32_16x16x32_bf16(ah[m], bh[n],
                                                            acc[m][n], 0, 0, 0);
        acc[m][n] = __builtin_amdgcn_mfma_f32_16x16x32_bf16(ah[m], bl[n],
                                                            acc[m][n], 0, 0, 0);
        acc[m][n] = __builtin_amdgcn_mfma_f32_16x16x32_bf16(al[m], bh[n],
                                                            acc[m][n], 0, 0, 0);
      }
  };

  // prologue: tile 0
  {
    f32x4 a0 = *(const f32x4*)gA;
    stageB(0);
    writeA(0, a0);  // compiler inserts vmcnt wait for a0 regs
    asm volatile("s_waitcnt vmcnt(0) lgkmcnt(0)" ::: "memory");
    __builtin_amdgcn_s_barrier();
    __builtin_amdgcn_sched_barrier(0);
  }
  for (int t = 0; t < NT; ++t) {
    f32x4 an;
    if (t < NT - 1) {
      an = *(const f32x4*)(gA + (t + 1) * 32);  // issue before compute
      stageB(t + 1);                            // DMA flies under MFMAs
    }
    compute(t);
    if (t < NT - 1) {
      writeA(t + 1, an);
      asm volatile("s_waitcnt vmcnt(0) lgkmcnt(0)" ::: "memory");
      __builtin_amdgcn_s_barrier();
      __builtin_amdgcn_sched_barrier(0);
    }
  }

  // ==== fused masked-softmax epilogue ====
  // lane holds rows r = wr + m*16 + (lane>>4)*4 + j, cols c = wc + n*16 + fr.
  // NT even -> last compute read buf1; buf0 region free for reductions.
  float* red = (float*)smem;         // [64][4] rowmax partials
  float* red2 = red + 256;           // [64][4][2] Z/Sm partials
  const int* qm = qmask + z * Q_;
  float mk[8];
#pragma unroll
  for (int n = 0; n < 8; ++n) mk[n] = (float)qm[wc + n * 16 + fr];

  int rb = wr + (lane >> 4) * 4;  // + m*16 + j
  float rmax[2][4];
#pragma unroll
  for (int m = 0; m < 2; ++m)
#pragma unroll
    for (int j = 0; j < 4; ++j) {
      float v = acc[m][0][j] * mk[0];
#pragma unroll
      for (int n = 1; n < 8; ++n) v = fmaxf(v, acc[m][n][j] * mk[n]);
      v = fmaxf(v, __shfl_xor(v, 1, 64));
      v = fmaxf(v, __shfl_xor(v, 2, 64));
      v = fmaxf(v, __shfl_xor(v, 4, 64));
      v = fmaxf(v, __shfl_xor(v, 8, 64));
      rmax[m][j] = v;
      if (fr == 0) red[(rb + m * 16 + j) * 4 + (wv & 3)] = v;
    }
  __syncthreads();
#pragma unroll
  for (int m = 0; m < 2; ++m)
#pragma unroll
    for (int j = 0; j < 4; ++j) {
      int r = rb + m * 16 + j;
      float v = fmaxf(fmaxf(red[r * 4], red[r * 4 + 1]),
                      fmaxf(red[r * 4 + 2], red[r * 4 + 3]));
      rmax[m][j] = v;
    }
  // e = exp(t - c) (masked-out cols contribute exp(-c) to Z, per reference)
  float Zp[2][4], Sp[2][4];
#pragma unroll
  for (int m = 0; m < 2; ++m)
#pragma unroll
    for (int j = 0; j < 4; ++j) {
      float zs = 0.f, ss = 0.f;
#pragma unroll
      for (int n = 0; n < 8; ++n) {
        float e = expf(acc[m][n][j] * mk[n] - rmax[m][j]);
        acc[m][n][j] = e;
        zs += e;
        ss += e * mk[n];
      }
      zs += __shfl_xor(zs, 1, 64); ss += __shfl_xor(ss, 1, 64);
      zs += __shfl_xor(zs, 2, 64); ss += __shfl_xor(ss, 2, 64);
      zs += __shfl_xor(zs, 4, 64); ss += __shfl_xor(ss, 4, 64);
      zs += __shfl_xor(zs, 8, 64); ss += __shfl_xor(ss, 8, 64);
      Zp[m][j] = zs;
      Sp[m][j] = ss;
      if (fr == 0) {
        red2[((rb + m * 16 + j) * 4 + (wv & 3)) * 2] = zs;
        red2[((rb + m * 16 + j) * 4 + (wv & 3)) * 2 + 1] = ss;
      }
    }
  __syncthreads();
  bf16* ap = alpha + ((long)(z * P_ + row0)) * Q_;
#pragma unroll
  for (int m = 0; m < 2; ++m)
#pragma unroll
    for (int j = 0; j < 4; ++j) {
      int r = rb + m * 16 + j;
      float Z = 0.f, Sm = 0.f;
#pragma unroll
      for (int w = 0; w < 4; ++w) {
        Z += red2[(r * 4 + w) * 2];
        Sm += red2[(r * 4 + w) * 2 + 1];
      }
      float inv = 1.0f / (Sm + 1e-13f * Z);
#pragma unroll
      for (int n = 0; n < 8; ++n)
        ap[(long)r * Q_ + wc + n * 16 + fr] =
            (bf16)(acc[m][n][j] * mk[n] * inv);
    }
}

// ---- 256x256-tile deep-pipelined GEMM (unchanged from R3) ----
template <int EPI, int NT>
__global__ __launch_bounds__(512, 2) void k_gemm256(
    const bf16* __restrict__ A, const bf16* __restrict__ Bm,
    void* __restrict__ Cv, const float* __restrict__ bias, int N, int gx,
    int gy, long sA, long sB, long sC) {
  constexpr int K = NT * 32;
  __shared__ __align__(16) bf16 smem[65536];

  int nwg = gridDim.x;
  int orig = blockIdx.x;
  int wg = (orig & 7) * (nwg >> 3) + (orig >> 3);
  int bx = wg % gx;
  int tt = wg / gx;
  int by = tt % gy;
  int z = tt / gy;
  int row0 = by * 256, col0 = bx * 256;
  A += z * sA;
  Bm += z * sB;

  int tid = threadIdx.x, wv = tid >> 6, lane = tid & 63;

  bool isA = wv < 4;
  int u0 = (wv & 3) * 4;
  int srow = u0 * 16 + (lane >> 2);
  int sclog = ((lane & 3) ^ ((lane >> 3) & 3)) * 8;
  const bf16* sbaseG = isA ? A + (long)(row0 + srow) * K + sclog
                           : Bm + (long)(col0 + srow) * K + sclog;
  int sbaseL = (isA ? 0 : 8192) + u0 * 512;

  auto stage = [&](int tile) {
    const bf16* g = sbaseG + tile * 32;
    bf16* l = smem + (tile & 3) * 16384 + sbaseL;
#pragma unroll
    for (int j = 0; j < 4; ++j) gload_lds16(g + (long)j * 16 * K, l + j * 512);
  };

  int wr = (wv >> 2) * 128, wc = (wv & 3) * 64;
  int fr = lane & 15, kq = lane >> 4;
  int swz = (kq ^ ((fr >> 1) & 3)) * 8 + fr * 32;

  f32x4 acc[8][4] = {};
  auto compute = [&](int t) {
    const bf16* bufA = smem + (t & 3) * 16384;
    const bf16* bufB = bufA + 8192;
    bf16x8 af[8], bfr[4];
#pragma unroll
    for (int m = 0; m < 8; ++m)
      af[m] = *(const bf16x8*)(bufA + (wr + m * 16) * 32 + swz);
#pragma unroll
    for (int n = 0; n < 4; ++n)
      bfr[n] = *(const bf16x8*)(bufB + (wc + n * 16) * 32 + swz);
#pragma unroll
    for (int m = 0; m < 8; ++m)
#pragma unroll
      for (int n = 0; n < 4; ++n)
        acc[m][n] = __builtin_amdgcn_mfma_f32_16x16x32_bf16(af[m], bfr[n],
                                                            acc[m][n], 0, 0, 0);
  };

  stage(0);
  stage(1);
  stage(2);
  asm volatile("s_waitcnt vmcnt(8)" ::: "memory");
  __builtin_amdgcn_s_barrier();
  __builtin_amdgcn_sched_barrier(0);
  for (int t = 0; t < NT - 3; ++t) {
    stage(t + 3);
    compute(t);
    asm volatile("s_waitcnt vmcnt(8)" ::: "memory");
    __builtin_amdgcn_s_barrier();
    __builtin_amdgcn_sched_barrier(0);
  }
  compute(NT - 3);
  asm volatile("s_waitcnt vmcnt(4)" ::: "memory");
  __builtin_amdgcn_s_barrier();
  __builtin_amdgcn_sched_barrier(0);
  compute(NT - 2);
  asm volatile("s_waitcnt vmcnt(0)" ::: "memory");
  __builtin_amdgcn_s_barrier();
  __builtin_amdgcn_sched_barrier(0);
  compute(NT - 1);

  int r0 = row0 + wr + (lane >> 4) * 4;
  int c0 = col0 + wc + fr;
  if constexpr (EPI == 1) {
    bf16* C = (bf16*)Cv + z * sC;
#pragma unroll
    for (int m = 0; m < 8; ++m)
#pragma unroll
      for (int n = 0; n < 4; ++n)
#pragma unroll
        for (int j = 0; j < 4; ++j)
          C[(long)(r0 + m * 16 + j) * N + c0 + n * 16] = (bf16)acc[m][n][j];
  } else {
    float* C = (float*)Cv;
#pragma unroll
    for (int n = 0; n < 4; ++n) {
      float bv = bias[c0 + n * 16];
#pragma unroll
      for (int m = 0; m < 8; ++m)
#pragma unroll
        for (int j = 0; j < 4; ++j) {
          float v = acc[m][n][j] + bv;
          C[(long)(r0 + m * 16 + j) * N + c0 + n * 16] = fmaxf(v, 0.f);
        }
    }
  }
}

extern "C" void kernel_launch(void* const* d_in, const int* in_sizes, int n_in,
                              void* d_out, int out_size, void* d_ws,
                              size_t ws_size, hipStream_t stream) {
  const float* passage = (const float*)d_in[0];
  const float* question = (const float*)d_in[1];
  const int* qmask = (const int*)d_in[2];
  const float* mapW = (const float*)d_in[3];
  const float* mapb = (const float*)d_in[4];

  char* ws = (char*)d_ws;
  size_t off = 0;
  auto alloc = [&](size_t bytes) {
    void* p = ws + off;
    off += (bytes + 255) & ~(size_t)255;
    return p;
  };
  bf16* q_hi = (bf16*)alloc((size_t)B_ * Q_ * H_ * 2);
  bf16* q_lo = (bf16*)alloc((size_t)B_ * Q_ * H_ * 2);
  bf16* qT = (bf16*)alloc((size_t)B_ * H_ * Q_ * 2);
  bf16* w_bf = (bf16*)alloc((size_t)H_ * H_ * 2);
  bf16* alpha = (bf16*)alloc((size_t)B_ * P_ * Q_ * 2);
  bf16* O = (bf16*)alloc((size_t)B_ * P_ * H_ * 2);

  k_split<<<1024, 256, 0, stream>>>(question, q_hi, q_lo, B_ * Q_ * H_ / 4);
  k_cvt<<<512, 256, 0, stream>>>(mapW, w_bf, H_ * H_ / 4);
  k_transpose<<<dim3(H_ / 64, Q_ / 64, B_), 256, 0, stream>>>(question, qT);

  // fused: S = passage @ question^T (split precision) + masked softmax
  k_score_softmax<<<256, 512, 0, stream>>>(passage, q_hi, q_lo, qmask, alpha);

  // GEMM3: O = alpha @ question
  k_gemm256<1, Q_ / 32><<<256, 512, 0, stream>>>(
      alpha, qT, O, nullptr, H_, H_ / 256, P_ / 256, (long)P_ * Q_,
      (long)H_ * Q_, (long)P_ * H_);

  // GEMM4: Y = relu(O @ W^T + b)
  k_gemm256<2, H_ / 32><<<256, 512, 0, stream>>>(
      O, w_bf, d_out, mapb, H_, H_ / 256, (B_ * P_) / 256, 0, 0, 0);
}

// Round 5
// 136.291 us; speedup vs baseline: 1.5214x; 1.0597x over previous
//
#include <hip/hip_runtime.h>
#include <hip/hip_bf16.h>

typedef __bf16 bf16;
typedef __bf16 bf16x8 __attribute__((ext_vector_type(8)));
typedef __bf16 bf16x4 __attribute__((ext_vector_type(4)));
typedef float  f32x4  __attribute__((ext_vector_type(4)));

#define B_ 8
#define P_ 2048
#define Q_ 512
#define H_ 1024

__device__ __forceinline__ void gload_lds16(const void* g, void* l) {
  __builtin_amdgcn_global_load_lds(
      (const __attribute__((address_space(1))) void*)g,
      (__attribute__((address_space(3))) void*)l, 16, 0, 0);
}

// ---- f32 -> bf16 hi/lo split (question only) ----
__global__ __launch_bounds__(256) void k_split(const float* __restrict__ x,
                                               bf16* __restrict__ hi,
                                               bf16* __restrict__ lo, int n4) {
  int i = blockIdx.x * blockDim.x + threadIdx.x;
  int stride = gridDim.x * blockDim.x;
  for (; i < n4; i += stride) {
    f32x4 v = ((const f32x4*)x)[i];
    bf16x4 h, l;
#pragma unroll
    for (int j = 0; j < 4; ++j) {
      bf16 hj = (bf16)v[j];
      h[j] = hj;
      l[j] = (bf16)(v[j] - (float)hj);
    }
    ((bf16x4*)hi)[i] = h;
    ((bf16x4*)lo)[i] = l;
  }
}

__global__ __launch_bounds__(256) void k_cvt(const float* __restrict__ x,
                                             bf16* __restrict__ y, int n4) {
  int i = blockIdx.x * blockDim.x + threadIdx.x;
  int stride = gridDim.x * blockDim.x;
  for (; i < n4; i += stride) {
    f32x4 v = ((const f32x4*)x)[i];
    bf16x4 h;
#pragma unroll
    for (int j = 0; j < 4; ++j) h[j] = (bf16)v[j];
    ((bf16x4*)y)[i] = h;
  }
}

// ---- question [B,Q,H] f32 -> qT [B,H,Q] bf16 ----
__global__ __launch_bounds__(256) void k_transpose(const float* __restrict__ q,
                                                   bf16* __restrict__ qT) {
  __shared__ float t[64][65];
  int b = blockIdx.z;
  int h0 = blockIdx.x * 64, q0 = blockIdx.y * 64;
  int tid = threadIdx.x;
  int c4 = (tid & 15) * 4;
  int r16 = tid >> 4;
  const float* src = q + ((long)b * Q_ + q0) * H_ + h0;
#pragma unroll
  for (int i = 0; i < 4; ++i) {
    int r = r16 + i * 16;
    f32x4 v = *(const f32x4*)(src + (long)r * H_ + c4);
    t[c4 + 0][r] = v[0];
    t[c4 + 1][r] = v[1];
    t[c4 + 2][r] = v[2];
    t[c4 + 3][r] = v[3];
  }
  __syncthreads();
  bf16* dst = qT + ((long)b * H_ + h0) * Q_ + q0;
#pragma unroll
  for (int i = 0; i < 4; ++i) {
    int hr = r16 + i * 16;
    bf16x4 o;
#pragma unroll
    for (int j = 0; j < 4; ++j) o[j] = (bf16)t[hr][c4 + j];
    *(bf16x4*)(dst + (long)hr * Q_ + c4) = o;
  }
}

// ==== fused: S-tile (split-bf16) + masked softmax, 2-phase counted-vmcnt ====
// Block = 64 rows x 512 cols (full Q). 8 waves (2M x 4N), wave tile 32x128.
// Per K-tile (BK=32) two phases:
//  P1: ds_read ah/al/bh; stage Bh(t+1); load A(t+2)->reg; 32 MFMA (AhBh+AlBh)
//      -> s_waitcnt vmcnt(5) [Bl(t) landed] -> barrier
//  P2: ds_read bl; ds_write A(t+1) (T14, reg from 3 phases back); stage Bl(t+1);
//      16 MFMA (AhBl) -> s_waitcnt vmcnt(5) [Bh(t+1) landed] -> barrier
// LDS: A 2x4096 + Bh 2x16384 + Bl 2x16384 = 73728 elems = 144 KiB.
// Never drains vmcnt to 0 in steady state (T3/T4); T5 setprio around MFMAs.
__global__ __launch_bounds__(512) void k_score_softmax(
    const float* __restrict__ passage, const bf16* __restrict__ q_hi,
    const bf16* __restrict__ q_lo, const int* __restrict__ qmask,
    bf16* __restrict__ alpha) {
  constexpr int NT = H_ / 32;  // 32 K-tiles
  __shared__ __align__(16) bf16 smem[73728];

  int orig = blockIdx.x;  // 256 blocks
  int z = orig & 7;       // batch == XCD (T1): question panels L2-resident
  int row0 = (orig >> 3) * 64;

  int tid = threadIdx.x, wv = tid >> 6, lane = tid & 63;
  int fr = lane & 15;
  int kq = lane >> 4;
  int wr = (wv >> 2) * 32, wc = (wv & 3) * 128;
  int swz = (kq ^ ((fr >> 1) & 3)) * 8;

  // A staging: thread -> (row tid>>3 of 64, k-chunk (tid&7)*4)
  const float* gA =
      passage + ((long)(z * P_ + row0 + (tid >> 3))) * H_ + (tid & 7) * 4;
  int aw = (tid >> 3) * 32 + ((((tid & 7) >> 1) ^ ((tid >> 4) & 3)) * 8) +
           (tid & 1) * 4;  // chunk-XOR swizzled A elem addr (R4-verified)
  // B staging: 4 lanes/row, chunk pre-swizzled on the global source (rule 21)
  long broff = ((long)(z * Q_ + (tid >> 2))) * H_ +
               (((tid & 3) ^ ((tid >> 3) & 3)) * 8);
  const bf16* gBh = q_hi + broff;
  const bf16* gBl = q_lo + broff;

  auto stageBh = [&](int t) {
    const bf16* g = gBh + t * 32;
    bf16* l = smem + 8192 + (t & 1) * 16384 + wv * 512;
#pragma unroll
    for (int p = 0; p < 4; ++p)
      gload_lds16(g + (long)p * 128 * H_, l + p * 4096);
  };
  auto stageBl = [&](int t) {
    const bf16* g = gBl + t * 32;
    bf16* l = smem + 40960 + (t & 1) * 16384 + wv * 512;
#pragma unroll
    for (int p = 0; p < 4; ++p)
      gload_lds16(g + (long)p * 128 * H_, l + p * 4096);
  };
  auto writeA = [&](int t, f32x4 av) {
    bf16x4 h, l;
#pragma unroll
    for (int j = 0; j < 4; ++j) {
      h[j] = (bf16)av[j];
      l[j] = (bf16)(av[j] - (float)h[j]);
    }
    int bb = (t & 1) * 4096;
    *(bf16x4*)(smem + bb + aw) = h;
    *(bf16x4*)(smem + bb + 2048 + aw) = l;
  };

  f32x4 acc[2][8] = {};
  f32x4 areg[2];

  // ---- prologue: A(0),A(1) regs; Bh(0),Bl(0) staged; A(0) -> LDS ----
  areg[0] = *(const f32x4*)gA;
  areg[1] = *(const f32x4*)(gA + 32);
  stageBh(0);
  stageBl(0);
  writeA(0, areg[0]);  // implicit wait for A(0) only; B glds stay in flight
  asm volatile("s_waitcnt vmcnt(4) lgkmcnt(0)" ::: "memory");  // Bh(0) landed
  __builtin_amdgcn_s_barrier();
  __builtin_amdgcn_sched_barrier(0);

#pragma unroll
  for (int t = 0; t < NT; ++t) {
    const int par = t & 1;
    const bf16* Ab = smem + par * 4096;
    const bf16* Bhb = smem + 8192 + par * 16384;
    const bf16* Blb = smem + 40960 + par * 16384;

    // ---------- P1 ----------
    bf16x8 ah[2], al[2], bq[8];
#pragma unroll
    for (int m = 0; m < 2; ++m) {
      int ro = (wr + m * 16 + fr) * 32 + swz;
      ah[m] = *(const bf16x8*)(Ab + ro);
      al[m] = *(const bf16x8*)(Ab + 2048 + ro);
    }
#pragma unroll
    for (int n = 0; n < 8; ++n)
      bq[n] = *(const bf16x8*)(Bhb + (wc + n * 16 + fr) * 32 + swz);
    if (t + 1 < NT) stageBh(t + 1);                      // 4 glds
    if (t + 2 < NT) areg[par] = *(const f32x4*)(gA + (t + 2) * 32);  // 1 vmem
    __builtin_amdgcn_s_setprio(1);
#pragma unroll
    for (int m = 0; m < 2; ++m)
#pragma unroll
      for (int n = 0; n < 8; ++n) {
        acc[m][n] = __builtin_amdgcn_mfma_f32_16x16x32_bf16(ah[m], bq[n],
                                                            acc[m][n], 0, 0, 0);
        acc[m][n] = __builtin_amdgcn_mfma_f32_16x16x32_bf16(al[m], bq[n],
                                                            acc[m][n], 0, 0, 0);
      }
    __builtin_amdgcn_s_setprio(0);
    // wait: Bl(t) landed. younger = Bh(t+1)x4 + A(t+2)
    if (t < NT - 2)
      asm volatile("s_waitcnt vmcnt(5) lgkmcnt(0)" ::: "memory");
    else if (t == NT - 2)
      asm volatile("s_waitcnt vmcnt(4) lgkmcnt(0)" ::: "memory");
    else
      asm volatile("s_waitcnt vmcnt(0) lgkmcnt(0)" ::: "memory");
    __builtin_amdgcn_s_barrier();
    __builtin_amdgcn_sched_barrier(0);

    // ---------- P2 ----------
#pragma unroll
    for (int n = 0; n < 8; ++n)
      bq[n] = *(const bf16x8*)(Blb + (wc + n * 16 + fr) * 32 + swz);
    if (t + 1 < NT) {
      writeA(t + 1, areg[(t + 1) & 1]);  // reg loaded at P1(t-1): long landed
      stageBl(t + 1);                    // 4 glds
    }
    __builtin_amdgcn_s_setprio(1);
#pragma unroll
    for (int m = 0; m < 2; ++m)
#pragma unroll
      for (int n = 0; n < 8; ++n)
        acc[m][n] = __builtin_amdgcn_mfma_f32_16x16x32_bf16(ah[m], bq[n],
                                                            acc[m][n], 0, 0, 0);
    __builtin_amdgcn_s_setprio(0);
    if (t + 1 < NT) {
      // wait: Bh(t+1) landed. younger = A(t+2) + Bl(t+1)x4
      if (t < NT - 2)
        asm volatile("s_waitcnt vmcnt(5) lgkmcnt(0)" ::: "memory");
      else
        asm volatile("s_waitcnt vmcnt(4) lgkmcnt(0)" ::: "memory");
      __builtin_amdgcn_s_barrier();
      __builtin_amdgcn_sched_barrier(0);
    }
  }

  // ==== fused masked-softmax epilogue (R4-verified) ====
  float* red = (float*)smem;   // [64][4] rowmax partials (A region 0: free)
  float* red2 = red + 256;     // [64][4][2] Z/Sm partials
  const int* qm = qmask + z * Q_;
  float mk[8];
#pragma unroll
  for (int n = 0; n < 8; ++n) mk[n] = (float)qm[wc + n * 16 + fr];

  int rb = wr + (lane >> 4) * 4;
  float rmax[2][4];
#pragma unroll
  for (int m = 0; m < 2; ++m)
#pragma unroll
    for (int j = 0; j < 4; ++j) {
      float v = acc[m][0][j] * mk[0];
#pragma unroll
      for (int n = 1; n < 8; ++n) v = fmaxf(v, acc[m][n][j] * mk[n]);
      v = fmaxf(v, __shfl_xor(v, 1, 64));
      v = fmaxf(v, __shfl_xor(v, 2, 64));
      v = fmaxf(v, __shfl_xor(v, 4, 64));
      v = fmaxf(v, __shfl_xor(v, 8, 64));
      rmax[m][j] = v;
      if (fr == 0) red[(rb + m * 16 + j) * 4 + (wv & 3)] = v;
    }
  __syncthreads();
#pragma unroll
  for (int m = 0; m < 2; ++m)
#pragma unroll
    for (int j = 0; j < 4; ++j) {
      int r = rb + m * 16 + j;
      rmax[m][j] = fmaxf(fmaxf(red[r * 4], red[r * 4 + 1]),
                         fmaxf(red[r * 4 + 2], red[r * 4 + 3]));
    }
#pragma unroll
  for (int m = 0; m < 2; ++m)
#pragma unroll
    for (int j = 0; j < 4; ++j) {
      float zs = 0.f, ss = 0.f;
#pragma unroll
      for (int n = 0; n < 8; ++n) {
        float e = expf(acc[m][n][j] * mk[n] - rmax[m][j]);
        acc[m][n][j] = e;
        zs += e;
        ss += e * mk[n];
      }
      zs += __shfl_xor(zs, 1, 64); ss += __shfl_xor(ss, 1, 64);
      zs += __shfl_xor(zs, 2, 64); ss += __shfl_xor(ss, 2, 64);
      zs += __shfl_xor(zs, 4, 64); ss += __shfl_xor(ss, 4, 64);
      zs += __shfl_xor(zs, 8, 64); ss += __shfl_xor(ss, 8, 64);
      if (fr == 0) {
        red2[((rb + m * 16 + j) * 4 + (wv & 3)) * 2] = zs;
        red2[((rb + m * 16 + j) * 4 + (wv & 3)) * 2 + 1] = ss;
      }
    }
  __syncthreads();
  bf16* ap = alpha + ((long)(z * P_ + row0)) * Q_;
#pragma unroll
  for (int m = 0; m < 2; ++m)
#pragma unroll
    for (int j = 0; j < 4; ++j) {
      int r = rb + m * 16 + j;
      float Z = 0.f, Sm = 0.f;
#pragma unroll
      for (int w = 0; w < 4; ++w) {
        Z += red2[(r * 4 + w) * 2];
        Sm += red2[(r * 4 + w) * 2 + 1];
      }
      float inv = 1.0f / (Sm + 1e-13f * Z);
#pragma unroll
      for (int n = 0; n < 8; ++n)
        ap[(long)r * Q_ + wc + n * 16 + fr] =
            (bf16)(acc[m][n][j] * mk[n] * inv);
    }
}

// ---- 256x256-tile deep-pipelined GEMM (unchanged) ----
template <int EPI, int NT>
__global__ __launch_bounds__(512, 2) void k_gemm256(
    const bf16* __restrict__ A, const bf16* __restrict__ Bm,
    void* __restrict__ Cv, const float* __restrict__ bias, int N, int gx,
    int gy, long sA, long sB, long sC) {
  constexpr int K = NT * 32;
  __shared__ __align__(16) bf16 smem[65536];

  int nwg = gridDim.x;
  int orig = blockIdx.x;
  int wg = (orig & 7) * (nwg >> 3) + (orig >> 3);
  int bx = wg % gx;
  int tt = wg / gx;
  int by = tt % gy;
  int z = tt / gy;
  int row0 = by * 256, col0 = bx * 256;
  A += z * sA;
  Bm += z * sB;

  int tid = threadIdx.x, wv = tid >> 6, lane = tid & 63;

  bool isA = wv < 4;
  int u0 = (wv & 3) * 4;
  int srow = u0 * 16 + (lane >> 2);
  int sclog = ((lane & 3) ^ ((lane >> 3) & 3)) * 8;
  const bf16* sbaseG = isA ? A + (long)(row0 + srow) * K + sclog
                           : Bm + (long)(col0 + srow) * K + sclog;
  int sbaseL = (isA ? 0 : 8192) + u0 * 512;

  auto stage = [&](int tile) {
    const bf16* g = sbaseG + tile * 32;
    bf16* l = smem + (tile & 3) * 16384 + sbaseL;
#pragma unroll
    for (int j = 0; j < 4; ++j) gload_lds16(g + (long)j * 16 * K, l + j * 512);
  };

  int wr = (wv >> 2) * 128, wc = (wv & 3) * 64;
  int fr = lane & 15, kq = lane >> 4;
  int swz = (kq ^ ((fr >> 1) & 3)) * 8 + fr * 32;

  f32x4 acc[8][4] = {};
  auto compute = [&](int t) {
    const bf16* bufA = smem + (t & 3) * 16384;
    const bf16* bufB = bufA + 8192;
    bf16x8 af[8], bfr[4];
#pragma unroll
    for (int m = 0; m < 8; ++m)
      af[m] = *(const bf16x8*)(bufA + (wr + m * 16) * 32 + swz);
#pragma unroll
    for (int n = 0; n < 4; ++n)
      bfr[n] = *(const bf16x8*)(bufB + (wc + n * 16) * 32 + swz);
#pragma unroll
    for (int m = 0; m < 8; ++m)
#pragma unroll
      for (int n = 0; n < 4; ++n)
        acc[m][n] = __builtin_amdgcn_mfma_f32_16x16x32_bf16(af[m], bfr[n],
                                                            acc[m][n], 0, 0, 0);
  };

  stage(0);
  stage(1);
  stage(2);
  asm volatile("s_waitcnt vmcnt(8)" ::: "memory");
  __builtin_amdgcn_s_barrier();
  __builtin_amdgcn_sched_barrier(0);
  for (int t = 0; t < NT - 3; ++t) {
    stage(t + 3);
    compute(t);
    asm volatile("s_waitcnt vmcnt(8)" ::: "memory");
    __builtin_amdgcn_s_barrier();
    __builtin_amdgcn_sched_barrier(0);
  }
  compute(NT - 3);
  asm volatile("s_waitcnt vmcnt(4)" ::: "memory");
  __builtin_amdgcn_s_barrier();
  __builtin_amdgcn_sched_barrier(0);
  compute(NT - 2);
  asm volatile("s_waitcnt vmcnt(0)" ::: "memory");
  __builtin_amdgcn_s_barrier();
  __builtin_amdgcn_sched_barrier(0);
  compute(NT - 1);

  int r0 = row0 + wr + (lane >> 4) * 4;
  int c0 = col0 + wc + fr;
  if constexpr (EPI == 1) {
    bf16* C = (bf16*)Cv + z * sC;
#pragma unroll
    for (int m = 0; m < 8; ++m)
#pragma unroll
      for (int n = 0; n < 4; ++n)
#pragma unroll
        for (int j = 0; j < 4; ++j)
          C[(long)(r0 + m * 16 + j) * N + c0 + n * 16] = (bf16)acc[m][n][j];
  } else {
    float* C = (float*)Cv;
#pragma unroll
    for (int n = 0; n < 4; ++n) {
      float bv = bias[c0 + n * 16];
#pragma unroll
      for (int m = 0; m < 8; ++m)
#pragma unroll
        for (int j = 0; j < 4; ++j) {
          float v = acc[m][n][j] + bv;
          C[(long)(r0 + m * 16 + j) * N + c0 + n * 16] = fmaxf(v, 0.f);
        }
    }
  }
}

extern "C" void kernel_launch(void* const* d_in, const int* in_sizes, int n_in,
                              void* d_out, int out_size, void* d_ws,
                              size_t ws_size, hipStream_t stream) {
  const float* passage = (const float*)d_in[0];
  const float* question = (const float*)d_in[1];
  const int* qmask = (const int*)d_in[2];
  const float* mapW = (const float*)d_in[3];
  const float* mapb = (const float*)d_in[4];

  char* ws = (char*)d_ws;
  size_t off = 0;
  auto alloc = [&](size_t bytes) {
    void* p = ws + off;
    off += (bytes + 255) & ~(size_t)255;
    return p;
  };
  bf16* q_hi = (bf16*)alloc((size_t)B_ * Q_ * H_ * 2);
  bf16* q_lo = (bf16*)alloc((size_t)B_ * Q_ * H_ * 2);
  bf16* qT = (bf16*)alloc((size_t)B_ * H_ * Q_ * 2);
  bf16* w_bf = (bf16*)alloc((size_t)H_ * H_ * 2);
  bf16* alpha = (bf16*)alloc((size_t)B_ * P_ * Q_ * 2);
  bf16* O = (bf16*)alloc((size_t)B_ * P_ * H_ * 2);

  k_split<<<1024, 256, 0, stream>>>(question, q_hi, q_lo, B_ * Q_ * H_ / 4);
  k_cvt<<<512, 256, 0, stream>>>(mapW, w_bf, H_ * H_ / 4);
  k_transpose<<<dim3(H_ / 64, Q_ / 64, B_), 256, 0, stream>>>(question, qT);

  // fused: S = passage @ question^T (split precision) + masked softmax
  k_score_softmax<<<256, 512, 0, stream>>>(passage, q_hi, q_lo, qmask, alpha);

  // GEMM3: O = alpha @ question
  k_gemm256<1, Q_ / 32><<<256, 512, 0, stream>>>(
      alpha, qT, O, nullptr, H_, H_ / 256, P_ / 256, (long)P_ * Q_,
      (long)H_ * Q_, (long)P_ * H_);

  // GEMM4: Y = relu(O @ W^T + b)
  k_gemm256<2, H_ / 32><<<256, 512, 0, stream>>>(
      O, w_bf, d_out, mapb, H_, H_ / 256, (B_ * P_) / 256, 0, 0, 0);
}

// Round 7
// 121.633 us; speedup vs baseline: 1.7047x; 1.1205x over previous
//
#include <hip/hip_runtime.h>
#include <hip/hip_bf16.h>

typedef _Float16 f16;
typedef _Float16 f16x8 __attribute__((ext_vector_type(8)));
typedef _Float16 f16x4 __attribute__((ext_vector_type(4)));
typedef _Float16 f16x2 __attribute__((ext_vector_type(2)));
typedef float f32x4 __attribute__((ext_vector_type(4)));
typedef float f32x2 __attribute__((ext_vector_type(2)));

#define B_ 8
#define P_ 2048
#define Q_ 512
#define H_ 1024

__device__ __forceinline__ void gload_lds16(const void* g, void* l) {
  __builtin_amdgcn_global_load_lds(
      (const __attribute__((address_space(1))) void*)g,
      (__attribute__((address_space(3))) void*)l, 16, 0, 0);
}

// ---- f32 -> f16 convert (map_W) ----
__global__ __launch_bounds__(256) void k_cvt16(const float* __restrict__ x,
                                               f16* __restrict__ y, int n4) {
  int i = blockIdx.x * blockDim.x + threadIdx.x;
  int stride = gridDim.x * blockDim.x;
  for (; i < n4; i += stride) {
    f32x4 v = ((const f32x4*)x)[i];
    f16x4 h;
#pragma unroll
    for (int j = 0; j < 4; ++j) h[j] = (f16)v[j];
    ((f16x4*)y)[i] = h;
  }
}

// ---- question [B,Q,H] f32 -> qT [B,H,Q] f16 AND q16 [B,Q,H] f16 ----
__global__ __launch_bounds__(256) void k_transpose(const float* __restrict__ q,
                                                   f16* __restrict__ qT,
                                                   f16* __restrict__ q16) {
  __shared__ float t[64][65];
  int b = blockIdx.z;
  int h0 = blockIdx.x * 64, q0 = blockIdx.y * 64;
  int tid = threadIdx.x;
  int c4 = (tid & 15) * 4;
  int r16 = tid >> 4;
  const float* src = q + ((long)b * Q_ + q0) * H_ + h0;
  f16* d16 = q16 + ((long)b * Q_ + q0) * H_ + h0;
#pragma unroll
  for (int i = 0; i < 4; ++i) {
    int r = r16 + i * 16;
    f32x4 v = *(const f32x4*)(src + (long)r * H_ + c4);
    f16x4 s;
#pragma unroll
    for (int j = 0; j < 4; ++j) s[j] = (f16)v[j];
    *(f16x4*)(d16 + (long)r * H_ + c4) = s;  // straight f16 copy
    t[c4 + 0][r] = v[0];
    t[c4 + 1][r] = v[1];
    t[c4 + 2][r] = v[2];
    t[c4 + 3][r] = v[3];
  }
  __syncthreads();
  f16* dst = qT + ((long)b * H_ + h0) * Q_ + q0;
#pragma unroll
  for (int i = 0; i < 4; ++i) {
    int hr = r16 + i * 16;
    f16x4 o;
#pragma unroll
    for (int j = 0; j < 4; ++j) o[j] = (f16)t[hr][c4 + j];
    *(f16x4*)(dst + (long)hr * Q_ + c4) = o;
  }
}

// ==== fused: S-tile (f16 single-pass) + masked softmax ====
// Block = 32 rows x 512 cols (full Q). 512 thr / 8 waves, wave tile 32x64.
// LDS 68 KiB (A 2x1024 + B 2x16384 f16) -> 2 blocks/CU. Per tile:
// stage B(t+1) FIRST (full-tile flight), ds_read A/B, ds_write A(t+1)
// (T14 reg-staged f32->f16), load A(t+2)->reg, 8 MFMA, counted vmcnt(1)
// (A(t+2) stays in flight) + barrier. Never drains to 0 in steady state.
__global__ __launch_bounds__(512, 2) void k_score_softmax(
    const float* __restrict__ passage, const f16* __restrict__ q16,
    const int* __restrict__ qmask, f16* __restrict__ alpha) {
  constexpr int NT = H_ / 32;  // 32 K-tiles
  __shared__ __align__(16) f16 smem[2048 + 32768];  // 69632 B

  int orig = blockIdx.x;  // 512 blocks; batch == XCD (T1)
  int z = orig & 7;
  int row0 = (orig >> 3) * 32;

  int tid = threadIdx.x, wv = tid >> 6, lane = tid & 63;
  int fr = lane & 15, kq = lane >> 4;
  int wc = wv * 64;
  int swz = (kq ^ ((fr >> 1) & 3)) * 8;

  // A: each thread loads f32x2 (row tid>>4, cols (tid&15)*2)
  int arow = tid >> 4;
  int acol2 = (tid & 15) * 2;
  const float* gA = passage + ((long)(z * P_ + row0 + arow)) * H_ + acol2;
  int aw = arow * 32 + ((acol2 >> 3) ^ ((arow >> 1) & 3)) * 8 + (acol2 & 7);

  // B staging: 4 rounds, rows tid>>2 + p*128, chunk pre-swizzled (rule 21)
  const f16* gB = q16 + ((long)(z * Q_ + (tid >> 2))) * H_ +
                  (((tid & 3) ^ ((tid >> 3) & 3)) * 8);

  auto stageB = [&](int t) {
    const f16* g = gB + t * 32;
    f16* l = smem + 2048 + (t & 1) * 16384 + wv * 512;
#pragma unroll
    for (int p = 0; p < 4; ++p)
      gload_lds16(g + (long)p * 128 * H_, l + p * 4096);
  };
  auto writeA = [&](int t, f32x2 av) {
    f16x2 h;
    h[0] = (f16)av[0];
    h[1] = (f16)av[1];
    *(f16x2*)(smem + (t & 1) * 1024 + aw) = h;
  };

  f32x4 acc[2][4] = {};
  f32x2 areg0, areg1;  // named regs, static parity (rule 20)

  // prologue
  areg0 = *(const f32x2*)gA;         // A(0)
  stageB(0);                         // 4 glds
  areg1 = *(const f32x2*)(gA + 32);  // A(1)
  writeA(0, areg0);                  // compiler waits A(0) only (vmcnt(5))
  asm volatile("s_waitcnt vmcnt(1) lgkmcnt(0)" ::: "memory");  // B(0) landed
  __builtin_amdgcn_s_barrier();
  __builtin_amdgcn_sched_barrier(0);

#pragma unroll 2
  for (int t = 0; t < NT; ++t) {
    if (t + 1 < NT) stageB(t + 1);  // issue first: full-tile flight
    f16x8 af[2], bf[4];
    const f16* Ab = smem + (t & 1) * 1024;
    const f16* Bb = smem + 2048 + (t & 1) * 16384;
#pragma unroll
    for (int m = 0; m < 2; ++m)
      af[m] = *(const f16x8*)(Ab + (m * 16 + fr) * 32 + swz);
#pragma unroll
    for (int n = 0; n < 4; ++n)
      bf[n] = *(const f16x8*)(Bb + (wc + n * 16 + fr) * 32 + swz);
    if (t + 1 < NT)
      writeA(t + 1, ((t + 1) & 1) ? areg1 : areg0);  // auto vmcnt(4), ~1 tile
    if (t + 2 < NT) {
      f32x2 a = *(const f32x2*)(gA + (t + 2) * 32);
      if ((t + 2) & 1) areg1 = a; else areg0 = a;
    }
    __builtin_amdgcn_s_setprio(1);
#pragma unroll
    for (int m = 0; m < 2; ++m)
#pragma unroll
      for (int n = 0; n < 4; ++n)
        acc[m][n] = __builtin_amdgcn_mfma_f32_16x16x32_f16(af[m], bf[n],
                                                           acc[m][n], 0, 0, 0);
    __builtin_amdgcn_s_setprio(0);
    if (t < NT - 2)
      asm volatile("s_waitcnt vmcnt(1) lgkmcnt(0)" ::: "memory");
    else if (t == NT - 2)
      asm volatile("s_waitcnt vmcnt(0) lgkmcnt(0)" ::: "memory");
    if (t < NT - 1) {
      __builtin_amdgcn_s_barrier();
      __builtin_amdgcn_sched_barrier(0);
    }
  }

  // ==== fused masked-softmax epilogue (rows 32, 8 wave-partials/row) ====
  __syncthreads();  // all tile-31 ds_reads done before smem reuse
  float* red = (float*)smem;          // [32][8] rowmax partials
  float* red2 = red + 256;            // [32][8][2] Z/Sm partials
  const int* qm = qmask + z * Q_;
  float mk[4];
#pragma unroll
  for (int n = 0; n < 4; ++n) mk[n] = (float)qm[wc + n * 16 + fr];

  int rb = (lane >> 4) * 4;  // + m*16 + j
  float rmax[2][4];
#pragma unroll
  for (int m = 0; m < 2; ++m)
#pragma unroll
    for (int j = 0; j < 4; ++j) {
      float v = acc[m][0][j] * mk[0];
#pragma unroll
      for (int n = 1; n < 4; ++n) v = fmaxf(v, acc[m][n][j] * mk[n]);
      v = fmaxf(v, __shfl_xor(v, 1, 64));
      v = fmaxf(v, __shfl_xor(v, 2, 64));
      v = fmaxf(v, __shfl_xor(v, 4, 64));
      v = fmaxf(v, __shfl_xor(v, 8, 64));
      if (fr == 0) red[(rb + m * 16 + j) * 8 + wv] = v;
    }
  __syncthreads();
#pragma unroll
  for (int m = 0; m < 2; ++m)
#pragma unroll
    for (int j = 0; j < 4; ++j) {
      int r = rb + m * 16 + j;
      float v = red[r * 8];
#pragma unroll
      for (int w = 1; w < 8; ++w) v = fmaxf(v, red[r * 8 + w]);
      rmax[m][j] = v;
    }
#pragma unroll
  for (int m = 0; m < 2; ++m)
#pragma unroll
    for (int j = 0; j < 4; ++j) {
      float zs = 0.f, ss = 0.f;
#pragma unroll
      for (int n = 0; n < 4; ++n) {
        float e = expf(acc[m][n][j] * mk[n] - rmax[m][j]);
        acc[m][n][j] = e;
        zs += e;
        ss += e * mk[n];
      }
      zs += __shfl_xor(zs, 1, 64); ss += __shfl_xor(ss, 1, 64);
      zs += __shfl_xor(zs, 2, 64); ss += __shfl_xor(ss, 2, 64);
      zs += __shfl_xor(zs, 4, 64); ss += __shfl_xor(ss, 4, 64);
      zs += __shfl_xor(zs, 8, 64); ss += __shfl_xor(ss, 8, 64);
      if (fr == 0) {
        red2[((rb + m * 16 + j) * 8 + wv) * 2] = zs;
        red2[((rb + m * 16 + j) * 8 + wv) * 2 + 1] = ss;
      }
    }
  __syncthreads();
  f16* ap = alpha + ((long)(z * P_ + row0)) * Q_;
#pragma unroll
  for (int m = 0; m < 2; ++m)
#pragma unroll
    for (int j = 0; j < 4; ++j) {
      int r = rb + m * 16 + j;
      float Z = 0.f, Sm = 0.f;
#pragma unroll
      for (int w = 0; w < 8; ++w) {
        Z += red2[(r * 8 + w) * 2];
        Sm += red2[(r * 8 + w) * 2 + 1];
      }
      float inv = 1.0f / (Sm + 1e-13f * Z);
#pragma unroll
      for (int n = 0; n < 4; ++n)
        ap[(long)r * Q_ + wc + n * 16 + fr] = (f16)(acc[m][n][j] * mk[n] * inv);
    }
}

// ---- 256x256-tile deep-pipelined GEMM (R3-R5-proven), A[M,K]*B[N,K]^T, f16 ----
// Coverage: grid == gx*gy*nz tiles exactly (GEMM3: 4*8*8=256; GEMM4: 4*64*1=256).
template <int EPI, int NT>
__global__ __launch_bounds__(512, 2) void k_gemm256(
    const f16* __restrict__ A, const f16* __restrict__ Bm,
    void* __restrict__ Cv, const float* __restrict__ bias, int N, int gx,
    int gy, long sA, long sB, long sC) {
  constexpr int K = NT * 32;
  __shared__ __align__(16) f16 smem[65536];

  int nwg = gridDim.x;  // 256
  int orig = blockIdx.x;
  int wg = (orig & 7) * (nwg >> 3) + (orig >> 3);  // T1 bijective
  int bx = wg % gx;
  int tt = wg / gx;
  int by = tt % gy;
  int z = tt / gy;
  int row0 = by * 256, col0 = bx * 256;
  A += z * sA;
  Bm += z * sB;

  int tid = threadIdx.x, wv = tid >> 6, lane = tid & 63;

  bool isA = wv < 4;
  int u0 = (wv & 3) * 4;
  int srow = u0 * 16 + (lane >> 2);
  int sclog = ((lane & 3) ^ ((lane >> 3) & 3)) * 8;
  const f16* sbaseG = isA ? A + (long)(row0 + srow) * K + sclog
                          : Bm + (long)(col0 + srow) * K + sclog;
  int sbaseL = (isA ? 0 : 8192) + u0 * 512;

  auto stage = [&](int tile) {
    const f16* g = sbaseG + (long)tile * 32;
    f16* l = smem + (tile & 3) * 16384 + sbaseL;
#pragma unroll
    for (int j = 0; j < 4; ++j) gload_lds16(g + (long)j * 16 * K, l + j * 512);
  };

  int wr = (wv >> 2) * 128, wc = (wv & 3) * 64;
  int fr = lane & 15, kq = lane >> 4;
  int swz = (kq ^ ((fr >> 1) & 3)) * 8 + fr * 32;

  f32x4 acc[8][4] = {};
  auto compute = [&](int t) {
    const f16* bufA = smem + (t & 3) * 16384;
    const f16* bufB = bufA + 8192;
    f16x8 af[8], bfr[4];
#pragma unroll
    for (int m = 0; m < 8; ++m)
      af[m] = *(const f16x8*)(bufA + (wr + m * 16) * 32 + swz);
#pragma unroll
    for (int n = 0; n < 4; ++n)
      bfr[n] = *(const f16x8*)(bufB + (wc + n * 16) * 32 + swz);
#pragma unroll
    for (int m = 0; m < 8; ++m)
#pragma unroll
      for (int n = 0; n < 4; ++n)
        acc[m][n] = __builtin_amdgcn_mfma_f32_16x16x32_f16(af[m], bfr[n],
                                                           acc[m][n], 0, 0, 0);
  };

  stage(0);
  stage(1);
  stage(2);
  asm volatile("s_waitcnt vmcnt(8)" ::: "memory");
  __builtin_amdgcn_s_barrier();
  __builtin_amdgcn_sched_barrier(0);
  for (int t = 0; t < NT - 3; ++t) {
    stage(t + 3);
    compute(t);
    asm volatile("s_waitcnt vmcnt(8)" ::: "memory");
    __builtin_amdgcn_s_barrier();
    __builtin_amdgcn_sched_barrier(0);
  }
  compute(NT - 3);
  asm volatile("s_waitcnt vmcnt(4)" ::: "memory");
  __builtin_amdgcn_s_barrier();
  __builtin_amdgcn_sched_barrier(0);
  compute(NT - 2);
  asm volatile("s_waitcnt vmcnt(0)" ::: "memory");
  __builtin_amdgcn_s_barrier();
  __builtin_amdgcn_sched_barrier(0);
  compute(NT - 1);

  int r0 = row0 + wr + (lane >> 4) * 4;
  int c0 = col0 + wc + fr;
  if constexpr (EPI == 1) {
    f16* C = (f16*)Cv + z * sC;
#pragma unroll
    for (int m = 0; m < 8; ++m)
#pragma unroll
      for (int n = 0; n < 4; ++n)
#pragma unroll
        for (int j = 0; j < 4; ++j)
          C[(long)(r0 + m * 16 + j) * N + c0 + n * 16] = (f16)acc[m][n][j];
  } else {
    float* C = (float*)Cv;
#pragma unroll
    for (int n = 0; n < 4; ++n) {
      float bv = bias[c0 + n * 16];
#pragma unroll
      for (int m = 0; m < 8; ++m)
#pragma unroll
        for (int j = 0; j < 4; ++j) {
          float v = acc[m][n][j] + bv;
          C[(long)(r0 + m * 16 + j) * N + c0 + n * 16] = fmaxf(v, 0.f);
        }
    }
  }
}

extern "C" void kernel_launch(void* const* d_in, const int* in_sizes, int n_in,
                              void* d_out, int out_size, void* d_ws,
                              size_t ws_size, hipStream_t stream) {
  const float* passage = (const float*)d_in[0];
  const float* question = (const float*)d_in[1];
  const int* qmask = (const int*)d_in[2];
  const float* mapW = (const float*)d_in[3];
  const float* mapb = (const float*)d_in[4];

  char* ws = (char*)d_ws;
  size_t off = 0;
  auto alloc = [&](size_t bytes) {
    void* p = ws + off;
    off += (bytes + 255) & ~(size_t)255;
    return p;
  };
  f16* q16 = (f16*)alloc((size_t)B_ * Q_ * H_ * 2);
  f16* qT = (f16*)alloc((size_t)B_ * H_ * Q_ * 2);
  f16* w16 = (f16*)alloc((size_t)H_ * H_ * 2);
  f16* alpha = (f16*)alloc((size_t)B_ * P_ * Q_ * 2);
  f16* O = (f16*)alloc((size_t)B_ * P_ * H_ * 2);

  k_cvt16<<<512, 256, 0, stream>>>(mapW, w16, H_ * H_ / 4);
  k_transpose<<<dim3(H_ / 64, Q_ / 64, B_), 256, 0, stream>>>(question, qT,
                                                              q16);

  // fused: S = passage @ question^T (f16) + masked softmax -> alpha f16
  k_score_softmax<<<512, 512, 0, stream>>>(passage, q16, qmask, alpha);

  // GEMM3: O = alpha @ question  (4 x 8 x 8 = 256 tiles == 256 blocks)
  k_gemm256<1, Q_ / 32><<<256, 512, 0, stream>>>(
      alpha, qT, O, nullptr, H_, H_ / 256, P_ / 256, (long)P_ * Q_,
      (long)H_ * Q_, (long)P_ * H_);

  // GEMM4: Y = relu(O @ W^T + b)  (4 x 64 x 1 = 256 tiles == 256 blocks)
  k_gemm256<2, H_ / 32><<<256, 512, 0, stream>>>(
      O, w16, d_out, mapb, H_, H_ / 256, (B_ * P_) / 256, 0, 0, 0);
}

// Round 8
// 116.714 us; speedup vs baseline: 1.7766x; 1.0421x over previous
//
#include <hip/hip_runtime.h>
#include <hip/hip_bf16.h>

typedef _Float16 f16;
typedef _Float16 f16x8 __attribute__((ext_vector_type(8)));
typedef _Float16 f16x4 __attribute__((ext_vector_type(4)));
typedef float f32x4 __attribute__((ext_vector_type(4)));
typedef int i32x4 __attribute__((ext_vector_type(4)));

#define B_ 8
#define P_ 2048
#define Q_ 512
#define H_ 1024

__device__ __forceinline__ void gload_lds16(const void* g, void* l) {
  __builtin_amdgcn_global_load_lds(
      (const __attribute__((address_space(1))) void*)g,
      (__attribute__((address_space(3))) void*)l, 16, 0, 0);
}

// ---- f32 -> f16 convert (map_W) ----
__global__ __launch_bounds__(256) void k_cvt16(const float* __restrict__ x,
                                               f16* __restrict__ y, int n4) {
  int i = blockIdx.x * blockDim.x + threadIdx.x;
  int stride = gridDim.x * blockDim.x;
  for (; i < n4; i += stride) {
    f32x4 v = ((const f32x4*)x)[i];
    f16x4 h;
#pragma unroll
    for (int j = 0; j < 4; ++j) h[j] = (f16)v[j];
    ((f16x4*)y)[i] = h;
  }
}

// ---- question [B,Q,H] f32 -> qT [B,H,Q] f16 AND q16 [B,Q,H] f16 ----
__global__ __launch_bounds__(256) void k_transpose(const float* __restrict__ q,
                                                   f16* __restrict__ qT,
                                                   f16* __restrict__ q16) {
  __shared__ float t[64][65];
  int b = blockIdx.z;
  int h0 = blockIdx.x * 64, q0 = blockIdx.y * 64;
  int tid = threadIdx.x;
  int c4 = (tid & 15) * 4;
  int r16 = tid >> 4;
  const float* src = q + ((long)b * Q_ + q0) * H_ + h0;
  f16* d16 = q16 + ((long)b * Q_ + q0) * H_ + h0;
#pragma unroll
  for (int i = 0; i < 4; ++i) {
    int r = r16 + i * 16;
    f32x4 v = *(const f32x4*)(src + (long)r * H_ + c4);
    f16x4 s;
#pragma unroll
    for (int j = 0; j < 4; ++j) s[j] = (f16)v[j];
    *(f16x4*)(d16 + (long)r * H_ + c4) = s;
    t[c4 + 0][r] = v[0];
    t[c4 + 1][r] = v[1];
    t[c4 + 2][r] = v[2];
    t[c4 + 3][r] = v[3];
  }
  __syncthreads();
  f16* dst = qT + ((long)b * H_ + h0) * Q_ + q0;
#pragma unroll
  for (int i = 0; i < 4; ++i) {
    int hr = r16 + i * 16;
    f16x4 o;
#pragma unroll
    for (int j = 0; j < 4; ++j) o[j] = (f16)t[hr][c4 + j];
    *(f16x4*)(dst + (long)hr * Q_ + c4) = o;
  }
}

// ==== GEMM1: S = passage @ question^T, 128x256 tile, f16 inputs, f32 out ====
// 512 thr / 8 waves (2M x 4N), wave tile 64x64, BK=32, NT=32.
// B (q16): 4-ring gload_lds (16 KB/tile), prefetch distance 3.
// A (passage f32): reg-staged 2 tiles ahead, f32->f16 cvt, ds_write 1 ahead
// (T14) -- kills any passage pre-conversion pass.
// Counted vmcnt(6) steady state: in flight = B(t+2)x2 + A(t+2)x2 + B(t+3)x2.
// LDS 80 KB: A dbuf 2x8KB + B ring 4x16KB. Batch == XCD (T1): question panel
// (1 MB) + passage rows stay L2-resident; B staged once per 128 output rows.
__global__ __launch_bounds__(512, 2) void k_gemm1(
    const float* __restrict__ passage, const f16* __restrict__ q16,
    float* __restrict__ S) {
  constexpr int NT = H_ / 32;  // 32 K-tiles
  __shared__ __align__(16) f16 smem[40960];  // 80 KB

  int orig = blockIdx.x;  // 256 blocks: gx=2 (col), gy=16 (row), z=8
  int wg = (orig & 7) * 32 + (orig >> 3);  // T1 bijective; z == XCD
  int bx = wg & 1, by = (wg >> 1) & 15, z = wg >> 5;
  int row0 = by * 128, col0 = bx * 256;

  int tid = threadIdx.x, wv = tid >> 6, lane = tid & 63;
  int fr = lane & 15, kq = lane >> 4;
  int wr = (wv >> 2) * 64, wc = (wv & 3) * 64;
  int swz = (kq ^ ((fr >> 1) & 3)) * 8;

  // A staging: row ar=tid>>2 (of 128), logical chunk ac=tid&3 (8 f32 each)
  int ar = tid >> 2, ac = tid & 3;
  const float* gA = passage + ((long)(z * P_ + row0 + ar)) * H_ + ac * 8;
  int aw = ar * 32 + ((ac ^ ((ar >> 1) & 3)) * 8);  // chunk-XOR swizzled

  // B staging: rows col0 + tid>>2 (+128 for 2nd gld), source chunk
  // pre-swizzled (rule 21); LDS dest linear row-major [256][32].
  const f16* gB = q16 + ((long)(z * Q_ + col0 + (tid >> 2))) * H_ +
                  (((tid & 3) ^ ((tid >> 3) & 3)) * 8);

  auto stageB = [&](int t) {
    const f16* g = gB + t * 32;
    f16* l = smem + 8192 + (t & 3) * 8192 + wv * 512;
    gload_lds16(g, l);
    gload_lds16(g + (long)128 * H_, l + 4096);
  };
  auto writeA = [&](int t, f32x4 lo, f32x4 hi) {
    f16x8 h;
#pragma unroll
    for (int j = 0; j < 4; ++j) {
      h[j] = (f16)lo[j];
      h[4 + j] = (f16)hi[j];
    }
    *(f16x8*)(smem + (t & 1) * 4096 + aw) = h;
  };

  f32x4 acc[4][4] = {};
  f32x4 a0lo, a0hi, a1lo, a1hi;  // named regs, static parity (rule 20)

  // prologue: A(0),A(1) -> regs; B(0..2) staged; A(0) -> LDS
  a0lo = *(const f32x4*)(gA);
  a0hi = *(const f32x4*)(gA + 4);
  a1lo = *(const f32x4*)(gA + 32);
  a1hi = *(const f32x4*)(gA + 36);
  stageB(0);
  stageB(1);
  stageB(2);
  writeA(0, a0lo, a0hi);  // implicit wait covers A(0) only
  asm volatile("s_waitcnt vmcnt(4) lgkmcnt(0)" ::: "memory");  // B(0) landed
  __builtin_amdgcn_s_barrier();
  __builtin_amdgcn_sched_barrier(0);

#pragma unroll 4
  for (int t = 0; t < NT; ++t) {
    if (t + 2 < NT) {  // A(t+2): parity (t+2)&1 == t&1
      const float* g = gA + (t + 2) * 32;
      if (t & 1) {
        a1lo = *(const f32x4*)(g);
        a1hi = *(const f32x4*)(g + 4);
      } else {
        a0lo = *(const f32x4*)(g);
        a0hi = *(const f32x4*)(g + 4);
      }
    }
    if (t + 3 < NT) stageB(t + 3);
    f16x8 af[4], bf[4];
    const f16* Ab = smem + (t & 1) * 4096;
    const f16* Bb = smem + 8192 + (t & 3) * 8192;
#pragma unroll
    for (int m = 0; m < 4; ++m)
      af[m] = *(const f16x8*)(Ab + (wr + m * 16 + fr) * 32 + swz);
#pragma unroll
    for (int n = 0; n < 4; ++n)
      bf[n] = *(const f16x8*)(Bb + (wc + n * 16 + fr) * 32 + swz);
    if (t + 1 < NT)  // A(t+1) parity: t even -> a1, t odd -> a0
      writeA(t + 1, (t & 1) ? a0lo : a1lo, (t & 1) ? a0hi : a1hi);
    __builtin_amdgcn_s_setprio(1);
#pragma unroll
    for (int m = 0; m < 4; ++m)
#pragma unroll
      for (int n = 0; n < 4; ++n)
        acc[m][n] = __builtin_amdgcn_mfma_f32_16x16x32_f16(af[m], bf[n],
                                                           acc[m][n], 0, 0, 0);
    __builtin_amdgcn_s_setprio(0);
    if (t <= NT - 4)
      asm volatile("s_waitcnt vmcnt(6) lgkmcnt(0)" ::: "memory");
    else if (t == NT - 3)
      asm volatile("s_waitcnt vmcnt(4) lgkmcnt(0)" ::: "memory");
    else
      asm volatile("s_waitcnt vmcnt(0) lgkmcnt(0)" ::: "memory");
    if (t < NT - 1) {
      __builtin_amdgcn_s_barrier();
      __builtin_amdgcn_sched_barrier(0);
    }
  }

  // epilogue: C/D layout col = lane&15, row = (lane>>4)*4 + j
  float* Sp = S + (long)z * P_ * Q_;
  int r0 = row0 + wr + (lane >> 4) * 4;
  int c0 = col0 + wc + fr;
#pragma unroll
  for (int m = 0; m < 4; ++m)
#pragma unroll
    for (int n = 0; n < 4; ++n)
#pragma unroll
      for (int j = 0; j < 4; ++j)
        Sp[(long)(r0 + m * 16 + j) * Q_ + c0 + n * 16] = acc[m][n][j];
}

// ---- masked softmax (R1-proven): alpha = m*e^{t-c}/(Sum(m*e) + 1e-13*Z) ----
__global__ __launch_bounds__(256) void k_softmax(const float* __restrict__ S,
                                                 const int* __restrict__ qmask,
                                                 f16* __restrict__ alpha) {
  int row = blockIdx.x * 4 + (threadIdx.x >> 6);
  int lane = threadIdx.x & 63;
  int b = row >> 11;  // P_=2048 rows per batch
  const float* s = S + (long)row * Q_;
  const int* mp = qmask + b * Q_;
  f32x4 v0 = ((const f32x4*)s)[lane * 2];
  f32x4 v1 = ((const f32x4*)s)[lane * 2 + 1];
  i32x4 m0 = ((const i32x4*)mp)[lane * 2];
  i32x4 m1 = ((const i32x4*)mp)[lane * 2 + 1];
  float t[8], mf[8];
#pragma unroll
  for (int j = 0; j < 4; ++j) {
    mf[j] = (float)m0[j];     t[j] = v0[j] * mf[j];
    mf[4 + j] = (float)m1[j]; t[4 + j] = v1[j] * mf[4 + j];
  }
  float mx = t[0];
#pragma unroll
  for (int j = 1; j < 8; ++j) mx = fmaxf(mx, t[j]);
  for (int o = 32; o; o >>= 1) mx = fmaxf(mx, __shfl_xor(mx, o, 64));
  float e[8], Z = 0.f, Sm = 0.f;
#pragma unroll
  for (int j = 0; j < 8; ++j) {
    e[j] = expf(t[j] - mx);
    Z += e[j];
    Sm += e[j] * mf[j];
  }
  for (int o = 32; o; o >>= 1) {
    Z += __shfl_xor(Z, o, 64);
    Sm += __shfl_xor(Sm, o, 64);
  }
  float inv = 1.0f / (Sm + 1e-13f * Z);
  f16x8 out;
#pragma unroll
  for (int j = 0; j < 8; ++j) out[j] = (f16)(e[j] * mf[j] * inv);
  *(f16x8*)(alpha + (long)row * Q_ + lane * 8) = out;
}

// ---- 256x256-tile deep-pipelined GEMM (R7-proven), A[M,K]*B[N,K]^T, f16 ----
template <int EPI, int NT>
__global__ __launch_bounds__(512, 2) void k_gemm256(
    const f16* __restrict__ A, const f16* __restrict__ Bm,
    void* __restrict__ Cv, const float* __restrict__ bias, int N, int gx,
    int gy, long sA, long sB, long sC) {
  constexpr int K = NT * 32;
  __shared__ __align__(16) f16 smem[65536];

  int nwg = gridDim.x;  // 256
  int orig = blockIdx.x;
  int wg = (orig & 7) * (nwg >> 3) + (orig >> 3);  // T1 bijective
  int bx = wg % gx;
  int tt = wg / gx;
  int by = tt % gy;
  int z = tt / gy;
  int row0 = by * 256, col0 = bx * 256;
  A += z * sA;
  Bm += z * sB;

  int tid = threadIdx.x, wv = tid >> 6, lane = tid & 63;

  bool isA = wv < 4;
  int u0 = (wv & 3) * 4;
  int srow = u0 * 16 + (lane >> 2);
  int sclog = ((lane & 3) ^ ((lane >> 3) & 3)) * 8;
  const f16* sbaseG = isA ? A + (long)(row0 + srow) * K + sclog
                          : Bm + (long)(col0 + srow) * K + sclog;
  int sbaseL = (isA ? 0 : 8192) + u0 * 512;

  auto stage = [&](int tile) {
    const f16* g = sbaseG + (long)tile * 32;
    f16* l = smem + (tile & 3) * 16384 + sbaseL;
#pragma unroll
    for (int j = 0; j < 4; ++j) gload_lds16(g + (long)j * 16 * K, l + j * 512);
  };

  int wr = (wv >> 2) * 128, wc = (wv & 3) * 64;
  int fr = lane & 15, kq = lane >> 4;
  int swz = (kq ^ ((fr >> 1) & 3)) * 8 + fr * 32;

  f32x4 acc[8][4] = {};
  auto compute = [&](int t) {
    const f16* bufA = smem + (t & 3) * 16384;
    const f16* bufB = bufA + 8192;
    f16x8 af[8], bfr[4];
#pragma unroll
    for (int m = 0; m < 8; ++m)
      af[m] = *(const f16x8*)(bufA + (wr + m * 16) * 32 + swz);
#pragma unroll
    for (int n = 0; n < 4; ++n)
      bfr[n] = *(const f16x8*)(bufB + (wc + n * 16) * 32 + swz);
#pragma unroll
    for (int m = 0; m < 8; ++m)
#pragma unroll
      for (int n = 0; n < 4; ++n)
        acc[m][n] = __builtin_amdgcn_mfma_f32_16x16x32_f16(af[m], bfr[n],
                                                           acc[m][n], 0, 0, 0);
  };

  stage(0);
  stage(1);
  stage(2);
  asm volatile("s_waitcnt vmcnt(8)" ::: "memory");
  __builtin_amdgcn_s_barrier();
  __builtin_amdgcn_sched_barrier(0);
  for (int t = 0; t < NT - 3; ++t) {
    stage(t + 3);
    compute(t);
    asm volatile("s_waitcnt vmcnt(8)" ::: "memory");
    __builtin_amdgcn_s_barrier();
    __builtin_amdgcn_sched_barrier(0);
  }
  compute(NT - 3);
  asm volatile("s_waitcnt vmcnt(4)" ::: "memory");
  __builtin_amdgcn_s_barrier();
  __builtin_amdgcn_sched_barrier(0);
  compute(NT - 2);
  asm volatile("s_waitcnt vmcnt(0)" ::: "memory");
  __builtin_amdgcn_s_barrier();
  __builtin_amdgcn_sched_barrier(0);
  compute(NT - 1);

  int r0 = row0 + wr + (lane >> 4) * 4;
  int c0 = col0 + wc + fr;
  if constexpr (EPI == 1) {
    f16* C = (f16*)Cv + z * sC;
#pragma unroll
    for (int m = 0; m < 8; ++m)
#pragma unroll
      for (int n = 0; n < 4; ++n)
#pragma unroll
        for (int j = 0; j < 4; ++j)
          C[(long)(r0 + m * 16 + j) * N + c0 + n * 16] = (f16)acc[m][n][j];
  } else {
    float* C = (float*)Cv;
#pragma unroll
    for (int n = 0; n < 4; ++n) {
      float bv = bias[c0 + n * 16];
#pragma unroll
      for (int m = 0; m < 8; ++m)
#pragma unroll
        for (int j = 0; j < 4; ++j) {
          float v = acc[m][n][j] + bv;
          C[(long)(r0 + m * 16 + j) * N + c0 + n * 16] = fmaxf(v, 0.f);
        }
    }
  }
}

extern "C" void kernel_launch(void* const* d_in, const int* in_sizes, int n_in,
                              void* d_out, int out_size, void* d_ws,
                              size_t ws_size, hipStream_t stream) {
  const float* passage = (const float*)d_in[0];
  const float* question = (const float*)d_in[1];
  const int* qmask = (const int*)d_in[2];
  const float* mapW = (const float*)d_in[3];
  const float* mapb = (const float*)d_in[4];

  char* ws = (char*)d_ws;
  size_t off = 0;
  auto alloc = [&](size_t bytes) {
    void* p = ws + off;
    off += (bytes + 255) & ~(size_t)255;
    return p;
  };
  f16* q16 = (f16*)alloc((size_t)B_ * Q_ * H_ * 2);
  f16* qT = (f16*)alloc((size_t)B_ * H_ * Q_ * 2);
  f16* w16 = (f16*)alloc((size_t)H_ * H_ * 2);
  f16* alpha = (f16*)alloc((size_t)B_ * P_ * Q_ * 2);
  f16* O = (f16*)alloc((size_t)B_ * P_ * H_ * 2);
  float* S = (float*)alloc((size_t)B_ * P_ * Q_ * 4);

  k_cvt16<<<512, 256, 0, stream>>>(mapW, w16, H_ * H_ / 4);
  k_transpose<<<dim3(H_ / 64, Q_ / 64, B_), 256, 0, stream>>>(question, qT,
                                                              q16);

  // GEMM1: S = passage @ question^T  (2 x 16 x 8 = 256 tiles == 256 blocks)
  k_gemm1<<<256, 512, 0, stream>>>(passage, q16, S);

  // masked softmax -> alpha f16
  k_softmax<<<B_ * P_ / 4, 256, 0, stream>>>(S, qmask, alpha);

  // GEMM3: O = alpha @ question  (4 x 8 x 8 = 256 tiles == 256 blocks)
  k_gemm256<1, Q_ / 32><<<256, 512, 0, stream>>>(
      alpha, qT, O, nullptr, H_, H_ / 256, P_ / 256, (long)P_ * Q_,
      (long)H_ * Q_, (long)P_ * H_);

  // GEMM4: Y = relu(O @ W^T + b)  (4 x 64 x 1 = 256 tiles == 256 blocks)
  k_gemm256<2, H_ / 32><<<256, 512, 0, stream>>>(
      O, w16, d_out, mapb, H_, H_ / 256, (B_ * P_) / 256, 0, 0, 0);
}